// Round 5
// baseline (195.369 us; speedup 1.0000x reference)
//
#include <hip/hip_runtime.h>

// Quantum circuit sim, 8-amps-per-thread register blocking (fits the 64-VGPR
// cap the allocator insists on — R2-R4 all spilled a 16-amp design at
// VGPR_Count=64, 150 MB scratch traffic/dispatch; attributes didn't move it).
// B=256 blocks (1/CU), 1024 threads. State 2^14 complex64 in LDS (128 KiB).
// Each phase sweeps the state in 2 chunks of 8 amps/thread, in-place.
//   P1 layout: i = chunk<<13 | wave<<9 | lane<<3 | r
//     wires 5..10 = lane bits 5..0 (shfl_xor), wires 11..13 = r bits (reg)
//   P2 layout: i = r<<11 | lane<<5 | chunk<<4 | wave
//     wires 0..2 = r bits (reg), wires 3..4 = lane bits 5,4 (shfl)
//   CNOT chain: c=0,1 reg swaps; c=2 cond-shfl(32); c=3..7 composed bpermute
//   src=lane^((lane>>1)&31); c=8..12 folded into next P1 gather
//   x = y^((y>>1)&31) (prefix-xor identity, verified in R1-R4 kernels).
// LDS slot swizzle slot = i ^ ((i>>4)&15) ^ ((i>>8)&15): lane->bank-residue
// map has rank 4 for every access pattern (P1 st/ld, P1-gather ld, P2 st/ld)
// -> uniform 4 lanes/residue = b64 bandwidth floor, no conflicts.

#define NW      14
#define NSTATE  (1 << NW)
#define TPB     1024
#define NLAYERS 3
#define NGATES  (NLAYERS * NW)

__device__ __forceinline__ int swz(int i) {
    return i ^ ((i >> 4) & 15) ^ ((i >> 8) & 15);
}

// u[8] = {u00x,u00y, u01x,u01y, u10x,u10y, u11x,u11y}
__device__ __forceinline__ void pairgate(float2& a, float2& d, const float (&u)[8]) {
    float2 na, nd;
    na.x = u[0]*a.x - u[1]*a.y + u[2]*d.x - u[3]*d.y;
    na.y = u[0]*a.y + u[1]*a.x + u[2]*d.y + u[3]*d.x;
    nd.x = u[4]*a.x - u[5]*a.y + u[6]*d.x - u[7]*d.y;
    nd.y = u[4]*a.y + u[5]*a.x + u[6]*d.y + u[7]*d.x;
    a = na; d = nd;
}

template <int M>
__device__ __forceinline__ void reg_gate8(float2 (&amps)[8], const float (&u)[8]) {
#pragma unroll
    for (int r = 0; r < 8; ++r)
        if (!(r & M)) pairgate(amps[r], amps[r | M], u);
}

template <int MASK>
__device__ __forceinline__ void lane_gate8(float2 (&amps)[8], const float (&u)[8], int lane) {
    const bool hi = (lane & MASK) != 0;
    const float c0x = hi ? u[6] : u[0];
    const float c0y = hi ? u[7] : u[1];
    const float c1x = hi ? u[4] : u[2];
    const float c1y = hi ? u[5] : u[3];
#pragma unroll
    for (int r = 0; r < 8; ++r) {
        const float mx = amps[r].x, my = amps[r].y;
        const float px = __shfl_xor(mx, MASK, 64);
        const float py = __shfl_xor(my, MASK, 64);
        amps[r].x = c0x*mx - c0y*my + c1x*px - c1y*py;
        amps[r].y = c0x*my + c0y*mx + c1x*py + c1y*px;
    }
}

__device__ __forceinline__ void load_u(const float4* gt4, int g, float (&u)[8]) {
    const float4 A = gt4[2*g], B = gt4[2*g+1];
    u[0]=A.x; u[1]=A.y; u[2]=A.z; u[3]=A.w;
    u[4]=B.x; u[5]=B.y; u[6]=B.z; u[7]=B.w;
}

__global__ void __launch_bounds__(TPB)
qsim_kernel(const float* __restrict__ state_batch,   // [B, NW]
            const float* __restrict__ var_params,    // [NLAYERS, NW, 3]
            const float* __restrict__ head_w,        // [NW]
            const float* __restrict__ head_b,        // [1]
            float* __restrict__ out)                 // [B]
{
    __shared__ float2 psi[NSTATE];          // 128 KiB
    __shared__ float4 gt4[NGATES * 2];      // fused RY*RZ matrices, 2 float4 each
    __shared__ float  rxc[NW], rxs[NW], hws[NW];
    __shared__ float  red[TPB / 64];

    const int t    = threadIdx.x;
    const int lane = t & 63;
    const int wave = t >> 6;
    const int b    = blockIdx.x;

    // ---- stage sample angles, gate matrices, head weights ----
    if (t < NW) {
        float s, c; sincosf(0.5f * state_batch[b * NW + t], &s, &c);
        rxc[t] = c; rxs[t] = s;
    }
    if (t >= 64 && t < 64 + NGATES) {
        const int g = t - 64;               // g = l*NW + w
        float sa, ca, sz, cz;
        sincosf(0.5f * var_params[g * 3 + 0], &sa, &ca);
        sincosf(0.5f * var_params[g * 3 + 1], &sz, &cz);
        gt4[2*g]   = make_float4( ca * cz, -ca * sz, -sa * cz,  sa * sz);
        gt4[2*g+1] = make_float4( sa * cz,  sa * sz,  ca * cz,  ca * sz);
    }
    if (t >= 128 && t < 128 + NW) hws[t - 128] = head_w[t - 128];
    __syncthreads();

    float2 amps[8];
    float  u[8];

#pragma unroll 1
    for (int l = 0; l < NLAYERS; ++l) {
        const int g0 = l * NW;

        // ================= P1 sweep: wires 5..13 =================
#pragma unroll 1
        for (int chunk = 0; chunk < 2; ++chunk) {
            const int base = (chunk << 13) | (wave << 9) | (lane << 3);

            if (l == 0) {
                // RX product state: amp(i) = (-i)^pop * prod_w (bit? s_w : c_w)
                float prodB = chunk ? rxs[0] : rxc[0];
                int   popB  = chunk;
#pragma unroll
                for (int j = 0; j < 4; ++j) {           // wires 1..4 = wave bits 3..0
                    const int bit = (wave >> (3 - j)) & 1;
                    prodB *= bit ? rxs[1 + j] : rxc[1 + j];
                    popB  += bit;
                }
#pragma unroll
                for (int k = 0; k < 6; ++k) {           // wires 5..10 = lane bits 5..0
                    const int bit = (lane >> (5 - k)) & 1;
                    prodB *= bit ? rxs[5 + k] : rxc[5 + k];
                    popB  += bit;
                }
#pragma unroll
                for (int r = 0; r < 8; ++r) {
                    float p = prodB; int pop = popB;
#pragma unroll
                    for (int m = 0; m < 3; ++m) {       // wires 11..13 = r bits 2..0
                        const int bit = (r >> (2 - m)) & 1;
                        p   *= bit ? rxs[11 + m] : rxc[11 + m];
                        pop += bit;
                    }
                    switch (pop & 3) {
                        case 0:  amps[r] = make_float2( p, 0.f); break;
                        case 1:  amps[r] = make_float2(0.f, -p); break;
                        case 2:  amps[r] = make_float2(-p, 0.f); break;
                        default: amps[r] = make_float2(0.f,  p); break;
                    }
                }
            } else {
                // gathered load folds prev layer's CNOT c=8..12
#pragma unroll
                for (int r = 0; r < 8; ++r) {
                    const int y = base | r;
                    amps[r] = psi[swz(y ^ ((y >> 1) & 31))];
                }
            }

            // wires 5..10: lane bits (masks 32..1)
            load_u(gt4, g0 + 5,  u); lane_gate8<32>(amps, u, lane);
            load_u(gt4, g0 + 6,  u); lane_gate8<16>(amps, u, lane);
            load_u(gt4, g0 + 7,  u); lane_gate8< 8>(amps, u, lane);
            load_u(gt4, g0 + 8,  u); lane_gate8< 4>(amps, u, lane);
            load_u(gt4, g0 + 9,  u); lane_gate8< 2>(amps, u, lane);
            load_u(gt4, g0 + 10, u); lane_gate8< 1>(amps, u, lane);
            // wires 11..13: reg bits
            load_u(gt4, g0 + 11, u); reg_gate8<4>(amps, u);
            load_u(gt4, g0 + 12, u); reg_gate8<2>(amps, u);
            load_u(gt4, g0 + 13, u); reg_gate8<1>(amps, u);

#pragma unroll
            for (int r = 0; r < 8; ++r)
                psi[swz(base | r)] = amps[r];
        }
        __syncthreads();

        // ================= P2 sweep: wires 0..4 + CNOTs =================
#pragma unroll 1
        for (int chunk = 0; chunk < 2; ++chunk) {
            const int base2 = (lane << 5) | (chunk << 4) | wave;

#pragma unroll
            for (int r = 0; r < 8; ++r)
                amps[r] = psi[swz((r << 11) | base2)];

            // wires 0..2: reg bits 2..0
            load_u(gt4, g0 + 0, u); reg_gate8<4>(amps, u);
            load_u(gt4, g0 + 1, u); reg_gate8<2>(amps, u);
            load_u(gt4, g0 + 2, u); reg_gate8<1>(amps, u);
            // wires 3,4: lane bits 5,4
            load_u(gt4, g0 + 3, u); lane_gate8<32>(amps, u, lane);
            load_u(gt4, g0 + 4, u); lane_gate8<16>(amps, u, lane);

            // CNOT c=0 (ctrl r2 -> tgt r1): swap (4,6),(5,7)
            { float2 tmp = amps[4]; amps[4] = amps[6]; amps[6] = tmp; }
            { float2 tmp = amps[5]; amps[5] = amps[7]; amps[7] = tmp; }
            // CNOT c=1 (ctrl r1 -> tgt r0): swap (2,3),(6,7)
            { float2 tmp = amps[2]; amps[2] = amps[3]; amps[3] = tmp; }
            { float2 tmp = amps[6]; amps[6] = amps[7]; amps[7] = tmp; }
            // CNOT c=2 (ctrl r0 -> tgt lane bit5): odd r swap across lane^32
#pragma unroll
            for (int r = 1; r < 8; r += 2) {
                amps[r].x = __shfl_xor(amps[r].x, 32, 64);
                amps[r].y = __shfl_xor(amps[r].y, 32, 64);
            }
            // CNOT c=3..7 composed (lane prefix-xor): src = lane^((lane>>1)&31)
            {
                const int src = lane ^ ((lane >> 1) & 31);
#pragma unroll
                for (int r = 0; r < 8; ++r) {
                    amps[r].x = __shfl(amps[r].x, src, 64);
                    amps[r].y = __shfl(amps[r].y, src, 64);
                }
            }

#pragma unroll
            for (int r = 0; r < 8; ++r)
                psi[swz((r << 11) | base2)] = amps[r];
        }
        __syncthreads();
    }

    // ---- measurement + head, folding final CNOT c=8..12 gather ----
    float acc = 0.f;
#pragma unroll 1
    for (int chunk = 0; chunk < 2; ++chunk) {
        const int base = (chunk << 13) | (wave << 9) | (lane << 3);
        float coefB = chunk ? -hws[0] : hws[0];
#pragma unroll
        for (int j = 0; j < 4; ++j)
            coefB += ((wave >> (3 - j)) & 1) ? -hws[1 + j] : hws[1 + j];
#pragma unroll
        for (int k = 0; k < 6; ++k)
            coefB += ((lane >> (5 - k)) & 1) ? -hws[5 + k] : hws[5 + k];
#pragma unroll
        for (int r = 0; r < 8; ++r) {
            const int y = base | r;
            const float2 v = psi[swz(y ^ ((y >> 1) & 31))];
            float cf = coefB;
#pragma unroll
            for (int m = 0; m < 3; ++m)
                cf += ((r >> (2 - m)) & 1) ? -hws[11 + m] : hws[11 + m];
            acc += (v.x * v.x + v.y * v.y) * cf;
        }
    }
#pragma unroll
    for (int off = 32; off > 0; off >>= 1)
        acc += __shfl_down(acc, off, 64);
    if (lane == 0) red[wave] = acc;
    __syncthreads();
    if (t == 0) {
        float s = 0.f;
#pragma unroll
        for (int i = 0; i < TPB / 64; ++i) s += red[i];
        out[b] = s + head_b[0];
    }
}

extern "C" void kernel_launch(void* const* d_in, const int* in_sizes, int n_in,
                              void* d_out, int out_size, void* d_ws, size_t ws_size,
                              hipStream_t stream) {
    const float* state_batch = (const float*)d_in[0];
    const float* var_params  = (const float*)d_in[1];
    const float* head_w      = (const float*)d_in[2];
    const float* head_b      = (const float*)d_in[3];
    float* out = (float*)d_out;
    qsim_kernel<<<dim3(out_size), dim3(TPB), 0, stream>>>(
        state_batch, var_params, head_w, head_b, out);
}

// Round 6
// 186.650 us; speedup vs baseline: 1.0467x; 1.0467x over previous
//
#include <hip/hip_runtime.h>

// Quantum circuit sim, fully SCALARIZED 8-amps-per-thread register blocking.
// R2-R5 post-mortem: per-thread arrays (amps[16]/amps[8]+u[8]) were demoted
// to scratch (SROA failure -> 150-347 MB HBM scratch traffic/dispatch at
// VGPR_Count=64). This version has NO indexable per-thread arrays: eight
// named float2 registers + named float4 gate rows, straight-line macros.
//
// B=256 blocks (1/CU), 1024 threads. State 2^14 complex64 in LDS (128 KiB).
// Wire w <-> bit (13-w). Two sweeps/layer, 2 chunks each, in-place:
//   P1 layout: i = chunk<<13 | wave<<9 | lane<<3 | r
//     wires 5..10 = lane bits 5..0 (shfl_xor), wires 11..13 = r bits 2..0
//   P2 layout: i = r<<11 | lane<<5 | chunk<<4 | wave
//     wires 0..2 = r bits 2..0, wires 3..4 = lane bits 5,4
//   CNOTs: c=0,1 reg swaps; c=2 cond-shfl(32); c=3..7 composed lane perm
//   src = lane^((lane>>1)&31); c=8..12 folded into next P1 gather
//   x = y^((y>>1)&31). All verified absmax=0 in R5.
// LDS swizzle slot = i ^ ((i>>4)&15) ^ ((i>>8)&15): rank-4 lane->bank map
// for every access pattern -> conflict-free (R5: conflicts 5.1M -> 0.79M).

#define NW      14
#define NSTATE  (1 << NW)
#define TPB     1024
#define NLAYERS 3
#define NGATES  (NLAYERS * NW)

__device__ __forceinline__ int swz(int i) {
    return i ^ ((i >> 4) & 15) ^ ((i >> 8) & 15);
}

// complex 2x2 gate on register pair (a,d).
// A = (u00x,u00y,u01x,u01y), B = (u10x,u10y,u11x,u11y)
__device__ __forceinline__ void pg(float2& a, float2& d, float4 A, float4 B) {
    const float nax = A.x*a.x - A.y*a.y + A.z*d.x - A.w*d.y;
    const float nay = A.x*a.y + A.y*a.x + A.z*d.y + A.w*d.x;
    const float ndx = B.x*a.x - B.y*a.y + B.z*d.x - B.w*d.y;
    const float ndy = B.x*a.y + B.y*a.x + B.z*d.y + B.w*d.x;
    a.x = nax; a.y = nay; d.x = ndx; d.y = ndy;
}

// lane-bit gate on one amp. C = (own_x, own_y, partner_x, partner_y)
__device__ __forceinline__ void lg(float2& a, int mask, float4 C) {
    const float px = __shfl_xor(a.x, mask, 64);
    const float py = __shfl_xor(a.y, mask, 64);
    const float nx = C.x*a.x - C.y*a.y + C.z*px - C.w*py;
    const float ny = C.x*a.y + C.y*a.x + C.z*py + C.w*px;
    a.x = nx; a.y = ny;
}

#define LANEG(g, mask) { \
    const float4 A_ = gt4[2*(g)], B_ = gt4[2*(g)+1]; \
    const float4 C_ = (lane & (mask)) ? make_float4(B_.z, B_.w, B_.x, B_.y) : A_; \
    lg(a0,(mask),C_); lg(a1,(mask),C_); lg(a2,(mask),C_); lg(a3,(mask),C_); \
    lg(a4,(mask),C_); lg(a5,(mask),C_); lg(a6,(mask),C_); lg(a7,(mask),C_); }

#define REGG4(g) { const float4 A_=gt4[2*(g)], B_=gt4[2*(g)+1]; \
    pg(a0,a4,A_,B_); pg(a1,a5,A_,B_); pg(a2,a6,A_,B_); pg(a3,a7,A_,B_); }
#define REGG2(g) { const float4 A_=gt4[2*(g)], B_=gt4[2*(g)+1]; \
    pg(a0,a2,A_,B_); pg(a1,a3,A_,B_); pg(a4,a6,A_,B_); pg(a5,a7,A_,B_); }
#define REGG1(g) { const float4 A_=gt4[2*(g)], B_=gt4[2*(g)+1]; \
    pg(a0,a1,A_,B_); pg(a2,a3,A_,B_); pg(a4,a5,A_,B_); pg(a6,a7,A_,B_); }

#define SWAP2(x, y) { const float2 t_ = x; x = y; y = t_; }

#define INITA(aX, b2, b1, b0) { \
    const float p_ = prodB * ((b2) ? s11 : c11) * ((b1) ? s12 : c12) * ((b0) ? s13 : c13); \
    const int pop_ = (popB + (b2) + (b1) + (b0)) & 3; \
    aX.x = (pop_ == 0) ? p_ : ((pop_ == 2) ? -p_ : 0.f); \
    aX.y = (pop_ == 1) ? -p_ : ((pop_ == 3) ? p_ : 0.f); }

#define GLOADP1(aX, r) { const int y_ = base | (r); aX = psi[swz(y_ ^ ((y_ >> 1) & 31))]; }
#define STOREP1(aX, r) psi[swz(base | (r))] = aX;
#define LDP2(aX, r)    aX = psi[swz(((r) << 11) | base2)];
#define STP2(aX, r)    psi[swz(((r) << 11) | base2)] = aX;

__global__ void __launch_bounds__(TPB)
qsim_kernel(const float* __restrict__ state_batch,   // [B, NW]
            const float* __restrict__ var_params,    // [NLAYERS, NW, 3]
            const float* __restrict__ head_w,        // [NW]
            const float* __restrict__ head_b,        // [1]
            float* __restrict__ out)                 // [B]
{
    __shared__ float2 psi[NSTATE];          // 128 KiB
    __shared__ float4 gt4[NGATES * 2];      // fused RY*RZ matrices
    __shared__ float  rxc[NW], rxs[NW], hws[NW];
    __shared__ float  red[TPB / 64];

    const int t    = threadIdx.x;
    const int lane = t & 63;
    const int wave = t >> 6;
    const int b    = blockIdx.x;

    // ---- stage sample angles, gate matrices, head weights ----
    if (t < NW) {
        float s, c; sincosf(0.5f * state_batch[b * NW + t], &s, &c);
        rxc[t] = c; rxs[t] = s;
    }
    if (t >= 64 && t < 64 + NGATES) {
        const int g = t - 64;               // g = l*NW + w
        float sa, ca, sz, cz;
        sincosf(0.5f * var_params[g * 3 + 0], &sa, &ca);
        sincosf(0.5f * var_params[g * 3 + 1], &sz, &cz);
        gt4[2*g]   = make_float4( ca * cz, -ca * sz, -sa * cz,  sa * sz);
        gt4[2*g+1] = make_float4( sa * cz,  sa * sz,  ca * cz,  ca * sz);
    }
    if (t >= 128 && t < 128 + NW) hws[t - 128] = head_w[t - 128];
    __syncthreads();

    float2 a0, a1, a2, a3, a4, a5, a6, a7;

#pragma unroll 1
    for (int l = 0; l < NLAYERS; ++l) {
        const int g0 = l * NW;

        // ================= P1 sweep: wires 5..13 =================
#pragma unroll 1
        for (int chunk = 0; chunk < 2; ++chunk) {
            const int base = (chunk << 13) | (wave << 9) | (lane << 3);

            if (l == 0) {
                // RX product state: amp(i) = (-i)^pop * prod_w (bit? s_w : c_w)
                float prodB = chunk ? rxs[0] : rxc[0];
                int   popB  = chunk;
                prodB *= (wave & 8) ? rxs[1] : rxc[1]; popB += (wave >> 3) & 1;
                prodB *= (wave & 4) ? rxs[2] : rxc[2]; popB += (wave >> 2) & 1;
                prodB *= (wave & 2) ? rxs[3] : rxc[3]; popB += (wave >> 1) & 1;
                prodB *= (wave & 1) ? rxs[4] : rxc[4]; popB +=  wave       & 1;
                prodB *= (lane & 32) ? rxs[5]  : rxc[5];  popB += (lane >> 5) & 1;
                prodB *= (lane & 16) ? rxs[6]  : rxc[6];  popB += (lane >> 4) & 1;
                prodB *= (lane &  8) ? rxs[7]  : rxc[7];  popB += (lane >> 3) & 1;
                prodB *= (lane &  4) ? rxs[8]  : rxc[8];  popB += (lane >> 2) & 1;
                prodB *= (lane &  2) ? rxs[9]  : rxc[9];  popB += (lane >> 1) & 1;
                prodB *= (lane &  1) ? rxs[10] : rxc[10]; popB +=  lane       & 1;
                const float s11 = rxs[11], c11 = rxc[11];
                const float s12 = rxs[12], c12 = rxc[12];
                const float s13 = rxs[13], c13 = rxc[13];
                INITA(a0, 0, 0, 0); INITA(a1, 0, 0, 1);
                INITA(a2, 0, 1, 0); INITA(a3, 0, 1, 1);
                INITA(a4, 1, 0, 0); INITA(a5, 1, 0, 1);
                INITA(a6, 1, 1, 0); INITA(a7, 1, 1, 1);
            } else {
                // gathered load folds prev layer's CNOT c=8..12
                GLOADP1(a0, 0); GLOADP1(a1, 1); GLOADP1(a2, 2); GLOADP1(a3, 3);
                GLOADP1(a4, 4); GLOADP1(a5, 5); GLOADP1(a6, 6); GLOADP1(a7, 7);
            }

            // wires 5..10: lane bits (masks 32..1)
            LANEG(g0 + 5, 32); LANEG(g0 + 6, 16); LANEG(g0 + 7, 8);
            LANEG(g0 + 8,  4); LANEG(g0 + 9,  2); LANEG(g0 + 10, 1);
            // wires 11..13: reg bits 2..0
            REGG4(g0 + 11); REGG2(g0 + 12); REGG1(g0 + 13);

            STOREP1(a0, 0); STOREP1(a1, 1); STOREP1(a2, 2); STOREP1(a3, 3);
            STOREP1(a4, 4); STOREP1(a5, 5); STOREP1(a6, 6); STOREP1(a7, 7);
        }
        __syncthreads();

        // ================= P2 sweep: wires 0..4 + CNOTs =================
#pragma unroll 1
        for (int chunk = 0; chunk < 2; ++chunk) {
            const int base2 = (lane << 5) | (chunk << 4) | wave;

            LDP2(a0, 0); LDP2(a1, 1); LDP2(a2, 2); LDP2(a3, 3);
            LDP2(a4, 4); LDP2(a5, 5); LDP2(a6, 6); LDP2(a7, 7);

            // wires 0..2: reg bits 2..0
            REGG4(g0 + 0); REGG2(g0 + 1); REGG1(g0 + 2);
            // wires 3,4: lane bits 5,4
            LANEG(g0 + 3, 32); LANEG(g0 + 4, 16);

            // CNOT c=0 (ctrl r2 -> tgt r1): swap (4,6),(5,7)
            SWAP2(a4, a6); SWAP2(a5, a7);
            // CNOT c=1 (ctrl r1 -> tgt r0): swap (2,3),(6,7)
            SWAP2(a2, a3); SWAP2(a6, a7);
            // CNOT c=2 (ctrl r0 -> tgt lane bit5): odd amps swap across lane^32
            a1.x = __shfl_xor(a1.x, 32, 64); a1.y = __shfl_xor(a1.y, 32, 64);
            a3.x = __shfl_xor(a3.x, 32, 64); a3.y = __shfl_xor(a3.y, 32, 64);
            a5.x = __shfl_xor(a5.x, 32, 64); a5.y = __shfl_xor(a5.y, 32, 64);
            a7.x = __shfl_xor(a7.x, 32, 64); a7.y = __shfl_xor(a7.y, 32, 64);
            // CNOT c=3..7 composed lane perm: src = lane ^ ((lane>>1)&31)
            {
                const int src = lane ^ ((lane >> 1) & 31);
                a0.x = __shfl(a0.x, src, 64); a0.y = __shfl(a0.y, src, 64);
                a1.x = __shfl(a1.x, src, 64); a1.y = __shfl(a1.y, src, 64);
                a2.x = __shfl(a2.x, src, 64); a2.y = __shfl(a2.y, src, 64);
                a3.x = __shfl(a3.x, src, 64); a3.y = __shfl(a3.y, src, 64);
                a4.x = __shfl(a4.x, src, 64); a4.y = __shfl(a4.y, src, 64);
                a5.x = __shfl(a5.x, src, 64); a5.y = __shfl(a5.y, src, 64);
                a6.x = __shfl(a6.x, src, 64); a6.y = __shfl(a6.y, src, 64);
                a7.x = __shfl(a7.x, src, 64); a7.y = __shfl(a7.y, src, 64);
            }

            STP2(a0, 0); STP2(a1, 1); STP2(a2, 2); STP2(a3, 3);
            STP2(a4, 4); STP2(a5, 5); STP2(a6, 6); STP2(a7, 7);
        }
        __syncthreads();
    }

    // ---- measurement + head, folding final CNOT c=8..12 gather ----
    const float h11 = hws[11], h12 = hws[12], h13 = hws[13];
    float acc = 0.f;
#pragma unroll 1
    for (int chunk = 0; chunk < 2; ++chunk) {
        const int base = (chunk << 13) | (wave << 9) | (lane << 3);
        float coefB = chunk ? -hws[0] : hws[0];
        coefB += (wave & 8) ? -hws[1] : hws[1];
        coefB += (wave & 4) ? -hws[2] : hws[2];
        coefB += (wave & 2) ? -hws[3] : hws[3];
        coefB += (wave & 1) ? -hws[4] : hws[4];
        coefB += (lane & 32) ? -hws[5]  : hws[5];
        coefB += (lane & 16) ? -hws[6]  : hws[6];
        coefB += (lane &  8) ? -hws[7]  : hws[7];
        coefB += (lane &  4) ? -hws[8]  : hws[8];
        coefB += (lane &  2) ? -hws[9]  : hws[9];
        coefB += (lane &  1) ? -hws[10] : hws[10];
#pragma unroll
        for (int r = 0; r < 8; ++r) {
            const int y = base | r;
            const float2 v = psi[swz(y ^ ((y >> 1) & 31))];
            float cf = coefB;
            cf += (r & 4) ? -h11 : h11;
            cf += (r & 2) ? -h12 : h12;
            cf += (r & 1) ? -h13 : h13;
            acc += (v.x * v.x + v.y * v.y) * cf;
        }
    }
#pragma unroll
    for (int off = 32; off > 0; off >>= 1)
        acc += __shfl_down(acc, off, 64);
    if (lane == 0) red[wave] = acc;
    __syncthreads();
    if (t == 0) {
        float s = 0.f;
#pragma unroll
        for (int i = 0; i < TPB / 64; ++i) s += red[i];
        out[b] = s + head_b[0];
    }
}

extern "C" void kernel_launch(void* const* d_in, const int* in_sizes, int n_in,
                              void* d_out, int out_size, void* d_ws, size_t ws_size,
                              hipStream_t stream) {
    const float* state_batch = (const float*)d_in[0];
    const float* var_params  = (const float*)d_in[1];
    const float* head_w      = (const float*)d_in[2];
    const float* head_b      = (const float*)d_in[3];
    float* out = (float*)d_out;
    qsim_kernel<<<dim3(out_size), dim3(TPB), 0, stream>>>(
        state_batch, var_params, head_w, head_b, out);
}

// Round 7
// 125.834 us; speedup vs baseline: 1.5526x; 1.4833x over previous
//
#include <hip/hip_runtime.h>

// Quantum circuit sim — radix-4 passes, canonical layout, R1-style small
// loop bodies (the only regime this toolchain compiled without mystery
// scratch traffic: R1 VGPR=52/no-HBM vs R2-R6 big-body kernels all pinned
// at VGPR=64 with 150-423 MB anomalous HBM traffic).
//
// B=256 blocks (1/CU), 1024 threads, state 2^14 complex64 in LDS (128 KiB).
// Wire w <-> bit (13-w). Per layer, 7 passes over adjacent wire pairs
// (2k,2k+1) = bits (SA,SB), SA=SB+1, SB=12-2k. Each thread owns quads
// (4 amps differing in bits SA,SB), applies both fused RZ*RY gates, then:
//   CNOT(2k-1,2k): ctrl = quad bit SB+2 -> predicated reg swap of SA-pairs
//   CNOT(2k,2k+1): unconditional swap of the ctrl=1 pair at store
// Chain order c=0..12 == pass order (1q gates on other wires commute with
// earlier CNOTs), so the full CNOT chain costs ZERO extra passes.
// RX encoding: product state amp(i) = (-i)^pop * prod_w (bit?s:c), computed
// directly in layer-0 pass-0 (no load). Measurement folds the linear head.
// 22 statevector passes total vs R1's 95.
//
// LDS swizzle slot = i ^ ((i>>4)&15) ^ ((i>>8)&15) — LINEAR over GF2, so
// neighbor slots = s00 ^ swz(bit). Rank-4 lane->bankpair map verified for
// all 7 insertion patterns + measurement sweep -> b64 conflict floor.

#define NW      14
#define NSTATE  (1 << NW)
#define NQUAD   (NSTATE >> 2)
#define TPB     1024
#define NLAYERS 3
#define NGATES  (NLAYERS * NW)

__device__ __forceinline__ int swz(int i) {
    return i ^ ((i >> 4) & 15) ^ ((i >> 8) & 15);
}

// complex 2x2 gate on (a,d): A=(u00x,u00y,u01x,u01y), B=(u10x,u10y,u11x,u11y)
__device__ __forceinline__ void pg(float2& a, float2& d, const float4 A, const float4 B) {
    const float nax = A.x*a.x - A.y*a.y + A.z*d.x - A.w*d.y;
    const float nay = A.x*a.y + A.y*a.x + A.z*d.y + A.w*d.x;
    const float ndx = B.x*a.x - B.y*a.y + B.z*d.x - B.w*d.y;
    const float ndy = B.x*a.y + B.y*a.x + B.z*d.y + B.w*d.x;
    a.x = nax; a.y = nay; d.x = ndx; d.y = ndy;
}

// (-i)^pop * p
__device__ __forceinline__ float2 mkamp(float p, int pop) {
    const int m = pop & 3;
    return make_float2((m == 0) ? p : ((m == 2) ? -p : 0.f),
                       (m == 1) ? -p : ((m == 3) ? p : 0.f));
}

__global__ void __launch_bounds__(TPB)
qsim_kernel(const float* __restrict__ state_batch,   // [B, NW]
            const float* __restrict__ var_params,    // [NLAYERS, NW, 3]
            const float* __restrict__ head_w,        // [NW]
            const float* __restrict__ head_b,        // [1]
            float* __restrict__ out)                 // [B]
{
    __shared__ float2 psi[NSTATE];          // 128 KiB
    __shared__ float4 gt4[NGATES * 2];      // fused RZ*RY matrices
    __shared__ float  rxc[NW], rxs[NW], hws[NW];
    __shared__ float  red[TPB / 64];

    const int t    = threadIdx.x;
    const int lane = t & 63;
    const int wave = t >> 6;
    const int b    = blockIdx.x;

    // ---- stage sample angles, gate matrices, head weights ----
    if (t < NW) {
        float s, c; sincosf(0.5f * state_batch[b * NW + t], &s, &c);
        rxc[t] = c; rxs[t] = s;
    }
    if (t >= 64 && t < 64 + NGATES) {
        const int g = t - 64;               // g = l*NW + w
        float sa, ca, sz, cz;
        sincosf(0.5f * var_params[g * 3 + 0], &sa, &ca);
        sincosf(0.5f * var_params[g * 3 + 1], &sz, &cz);
        gt4[2*g]   = make_float4( ca * cz, -ca * sz, -sa * cz,  sa * sz);
        gt4[2*g+1] = make_float4( sa * cz,  sa * sz,  ca * cz,  ca * sz);
    }
    if (t >= 128 && t < 128 + NW) hws[t - 128] = head_w[t - 128];
    __syncthreads();

#pragma unroll 1
    for (int l = 0; l < NLAYERS; ++l) {
        const int g0 = l * NW;

        // ---- pass 0: wires 0,1 (bits 13,12) + CNOT(0,1) ----
        {
            const float4 Aa = gt4[2*g0],     Ba = gt4[2*g0 + 1];
            const float4 Ab = gt4[2*g0 + 2], Bb = gt4[2*g0 + 3];
#pragma unroll 1
            for (int q = t; q < NQUAD; q += TPB) {
                const int s00 = swz(q);              // bits 12,13 of i00 are 0
                const int s01 = s00 ^ 0x1000;        // swz(1<<12) = 1<<12
                const int s10 = s00 ^ 0x2000;        // swz(1<<13) = 1<<13
                const int s11 = s00 ^ 0x3000;
                float2 a00, a01, a10, a11;
                if (l == 0) {
                    // RX product state for bits 0..11 (wires 2..13)
                    float base = 1.f; int pop = 0;
#pragma unroll
                    for (int w = 2; w < NW; ++w) {
                        const int bit = (q >> (13 - w)) & 1;
                        base *= bit ? rxs[w] : rxc[w];
                        pop += bit;
                    }
                    a00 = mkamp(rxc[0] * rxc[1] * base, pop);
                    a01 = mkamp(rxc[0] * rxs[1] * base, pop + 1);
                    a10 = mkamp(rxs[0] * rxc[1] * base, pop + 1);
                    a11 = mkamp(rxs[0] * rxs[1] * base, pop + 2);
                } else {
                    a00 = psi[s00]; a01 = psi[s01]; a10 = psi[s10]; a11 = psi[s11];
                }
                pg(a00, a10, Aa, Ba); pg(a01, a11, Aa, Ba);   // wire 0 (bit 13)
                pg(a00, a01, Ab, Bb); pg(a10, a11, Ab, Bb);   // wire 1 (bit 12)
                // CNOT(0,1): swap the ctrl=1 pair at store
                psi[s00] = a00; psi[s01] = a01; psi[s10] = a11; psi[s11] = a10;
            }
            __syncthreads();
        }

        // ---- passes k=1..6: wires 2k,2k+1 (bits SB+1,SB), SB=12-2k ----
#pragma unroll 1
        for (int k = 1; k <= 6; ++k) {
            const int SB = 12 - 2 * k;
            const int LO = 1 << SB;
            const int SL = swz(LO);                  // swz is linear
            const int SH = swz(LO << 1);
            const float4 Aa = gt4[2*(g0 + 2*k)],     Ba = gt4[2*(g0 + 2*k) + 1];
            const float4 Ab = gt4[2*(g0 + 2*k + 1)], Bb = gt4[2*(g0 + 2*k + 1) + 1];
#pragma unroll 1
            for (int q = t; q < NQUAD; q += TPB) {
                const int i00 = ((q >> SB) << (SB + 2)) | (q & (LO - 1));
                const int s00 = swz(i00);
                float2 a00 = psi[s00],      a01 = psi[s00 ^ SL];
                float2 a10 = psi[s00 ^ SH], a11 = psi[s00 ^ SH ^ SL];
                pg(a00, a10, Aa, Ba); pg(a01, a11, Aa, Ba);   // wire 2k   (bit SB+1)
                pg(a00, a01, Ab, Bb); pg(a10, a11, Ab, Bb);   // wire 2k+1 (bit SB)
                // CNOT(2k-1,2k): ctrl = bit SB+2 of i00 -> cond swap SA-pairs
                const bool cs = ((i00 >> (SB + 2)) & 1) != 0;
                const float2 n00 = cs ? a10 : a00;
                const float2 n10 = cs ? a00 : a10;
                const float2 n01 = cs ? a11 : a01;
                const float2 n11 = cs ? a01 : a11;
                // CNOT(2k,2k+1): swap the ctrl=1 pair at store
                psi[s00] = n00; psi[s00 ^ SL] = n01;
                psi[s00 ^ SH] = n11; psi[s00 ^ SH ^ SL] = n10;
            }
            __syncthreads();
        }
    }

    // ---- measurement + linear head (chain already complete) ----
    float coefLow = 0.f;                // i bits 0..9 = t -> wires 13..4
#pragma unroll
    for (int j = 0; j < 10; ++j)
        coefLow += ((t >> j) & 1) ? -hws[13 - j] : hws[13 - j];
    float acc = 0.f;
#pragma unroll 1
    for (int c = 0; c < NSTATE / TPB; ++c) {
        const int i = (c << 10) | t;    // i bits 10..13 = c bits 0..3 -> wires 3..0
        float coef = coefLow;
        coef += (c & 1) ? -hws[3] : hws[3];
        coef += (c & 2) ? -hws[2] : hws[2];
        coef += (c & 4) ? -hws[1] : hws[1];
        coef += (c & 8) ? -hws[0] : hws[0];
        const float2 v = psi[swz(i)];
        acc += (v.x * v.x + v.y * v.y) * coef;
    }
#pragma unroll
    for (int off = 32; off > 0; off >>= 1)
        acc += __shfl_down(acc, off, 64);
    if (lane == 0) red[wave] = acc;
    __syncthreads();
    if (t == 0) {
        float s = 0.f;
#pragma unroll
        for (int i = 0; i < TPB / 64; ++i) s += red[i];
        out[b] = s + head_b[0];
    }
}

extern "C" void kernel_launch(void* const* d_in, const int* in_sizes, int n_in,
                              void* d_out, int out_size, void* d_ws, size_t ws_size,
                              hipStream_t stream) {
    const float* state_batch = (const float*)d_in[0];
    const float* var_params  = (const float*)d_in[1];
    const float* head_w      = (const float*)d_in[2];
    const float* head_b      = (const float*)d_in[3];
    float* out = (float*)d_out;
    qsim_kernel<<<dim3(out_size), dim3(TPB), 0, stream>>>(
        state_batch, var_params, head_w, head_b, out);
}

// Round 8
// 106.798 us; speedup vs baseline: 1.8293x; 1.1782x over previous
//
#include <hip/hip_runtime.h>

// Quantum circuit sim — radix-4 passes (R7 structure, verified absmax=0),
// now with packed-fp32 gate math + address-XOR CNOT + fused final pass.
//
// R7 post-mortem: VALU-issue-bound (VALUBusy 78%, HBM ~0, conflicts ~7%).
// CDNA4 fp32 peak (157 TF) is the v_pk_fma_f32 PACKED rate — scalar is half.
// Amps are 2-wide float ext-vectors (re,im); each complex 2x2 gate row is
//   x00*a + (-y00,y00)*swap(a) + x01*d + (-y01,y01)*swap(d)
// = 8 pk-ops + 2 swaps vs 16 scalar ops. Gate scalars go through
// readfirstlane -> SGPRs so VOP3P broadcasts don't eat VGPRs.
//
// B=256 blocks (1/CU), 1024 threads, state 2^14 complex64 in LDS (128 KiB).
// Wire w <-> bit (13-w). 7 passes/layer over wire pairs (2k,2k+1), CNOT
// chain folded free:
//   CNOT(2k-1,2k) + CNOT(2k,2k+1) == single store-address XOR:
//   e = s00 ^ (cs ? SH^SL : 0); a00->e, a01->e^SL, a10->e^(SH^SL), a11->e^SH
//   (cs = bit SB+2 of i00; enumerated against R7's verified store pattern).
// Final pass (l=2, wires 12,13) fused with measurement: accumulates
// |amp|^2 * coef(dest index) from registers — no final store, no extra
// sweep, one less barrier. cs there = t&1 (thread-constant).
//
// LDS swizzle slot = i ^ ((i>>4)&15) ^ ((i>>8)&15), linear over GF2.
// Small dynamic loop bodies only — the R2-R6 big-body regime triggered
// pathological scratch spills (150-423 MB/dispatch) on this toolchain.

#define NW      14
#define NSTATE  (1 << NW)
#define NQUAD   (NSTATE >> 2)
#define TPB     1024
#define NLAYERS 3
#define NGATES  (NLAYERS * NW)

typedef float v2f __attribute__((ext_vector_type(2)));

__device__ __forceinline__ int swz(int i) {
    return i ^ ((i >> 4) & 15) ^ ((i >> 8) & 15);
}
__device__ __forceinline__ v2f vswp(v2f a) { return __builtin_shufflevector(a, a, 1, 0); }
__device__ __forceinline__ v2f vspl(float x) { v2f r; r.x = x;  r.y = x; return r; }
__device__ __forceinline__ v2f vpm(float x)  { v2f r; r.x = -x; r.y = x; return r; }
__device__ __forceinline__ float rfl(float x) {
    return __int_as_float(__builtin_amdgcn_readfirstlane(__float_as_int(x)));
}

// complex 2x2 gate on (a,d); row u0 = (x00+iy00, x01+iy01), row u1 likewise
__device__ __forceinline__ void pgp(v2f& a, v2f& d,
                                    float x00, float y00, float x01, float y01,
                                    float x10, float y10, float x11, float y11) {
    const v2f sa = vswp(a), sd = vswp(d);
    const v2f na = vspl(x00) * a + vpm(y00) * sa + vspl(x01) * d + vpm(y01) * sd;
    const v2f nd = vspl(x10) * a + vpm(y10) * sa + vspl(x11) * d + vpm(y11) * sd;
    a = na; d = nd;
}

// (-i)^pop * p
__device__ __forceinline__ v2f mkamp(float p, int pop) {
    const int m = pop & 3;
    v2f r;
    r.x = (m == 0) ? p : ((m == 2) ? -p : 0.f);
    r.y = (m == 1) ? -p : ((m == 3) ? p : 0.f);
    return r;
}

__global__ void __launch_bounds__(TPB)
qsim_kernel(const float* __restrict__ state_batch,   // [B, NW]
            const float* __restrict__ var_params,    // [NLAYERS, NW, 3]
            const float* __restrict__ head_w,        // [NW]
            const float* __restrict__ head_b,        // [1]
            float* __restrict__ out)                 // [B]
{
    __shared__ v2f    psi[NSTATE];          // 128 KiB
    __shared__ float4 gt4[NGATES * 2];      // fused RZ*RY matrices
    __shared__ float  rxc[NW], rxs[NW], hws[NW];
    __shared__ float  red[TPB / 64];

    const int t    = threadIdx.x;
    const int lane = t & 63;
    const int wave = t >> 6;
    const int b    = blockIdx.x;

    if (t < NW) {
        float s, c; sincosf(0.5f * state_batch[b * NW + t], &s, &c);
        rxc[t] = c; rxs[t] = s;
    }
    if (t >= 64 && t < 64 + NGATES) {
        const int g = t - 64;               // g = l*NW + w
        float sa, ca, sz, cz;
        sincosf(0.5f * var_params[g * 3 + 0], &sa, &ca);
        sincosf(0.5f * var_params[g * 3 + 1], &sz, &cz);
        gt4[2*g]   = make_float4( ca * cz, -ca * sz, -sa * cz,  sa * sz);
        gt4[2*g+1] = make_float4( sa * cz,  sa * sz,  ca * cz,  ca * sz);
    }
    if (t >= 128 && t < 128 + NW) hws[t - 128] = head_w[t - 128];
    __syncthreads();

#pragma unroll 1
    for (int l = 0; l < NLAYERS; ++l) {
        const int g0 = l * NW;

        // ---- pass 0: wires 0,1 (bits 13,12) + CNOT(0,1) ----
        {
            const float4 A0 = gt4[2*g0],     B0 = gt4[2*g0 + 1];
            const float4 A1 = gt4[2*g0 + 2], B1 = gt4[2*g0 + 3];
            const float ax0=rfl(A0.x), ay0=rfl(A0.y), az0=rfl(A0.z), aw0=rfl(A0.w);
            const float bx0=rfl(B0.x), by0=rfl(B0.y), bz0=rfl(B0.z), bw0=rfl(B0.w);
            const float ax1=rfl(A1.x), ay1=rfl(A1.y), az1=rfl(A1.z), aw1=rfl(A1.w);
            const float bx1=rfl(B1.x), by1=rfl(B1.y), bz1=rfl(B1.z), bw1=rfl(B1.w);
#pragma unroll 1
            for (int q = t; q < NQUAD; q += TPB) {
                const int s00 = swz(q);              // i00 = q (bits 12,13 zero)
                const int s01 = s00 ^ 0x1000;
                const int s10 = s00 ^ 0x2000;
                const int s11 = s00 ^ 0x3000;
                v2f a00, a01, a10, a11;
                if (l == 0) {
                    float base = 1.f; int pop = 0;
#pragma unroll
                    for (int w = 2; w < NW; ++w) {
                        const int bit = (q >> (13 - w)) & 1;
                        base *= bit ? rxs[w] : rxc[w];
                        pop += bit;
                    }
                    a00 = mkamp(rxc[0] * rxc[1] * base, pop);
                    a01 = mkamp(rxc[0] * rxs[1] * base, pop + 1);
                    a10 = mkamp(rxs[0] * rxc[1] * base, pop + 1);
                    a11 = mkamp(rxs[0] * rxs[1] * base, pop + 2);
                } else {
                    a00 = psi[s00]; a01 = psi[s01]; a10 = psi[s10]; a11 = psi[s11];
                }
                pgp(a00, a10, ax0,ay0,az0,aw0, bx0,by0,bz0,bw0);   // wire 0 (bit 13)
                pgp(a01, a11, ax0,ay0,az0,aw0, bx0,by0,bz0,bw0);
                pgp(a00, a01, ax1,ay1,az1,aw1, bx1,by1,bz1,bw1);   // wire 1 (bit 12)
                pgp(a10, a11, ax1,ay1,az1,aw1, bx1,by1,bz1,bw1);
                // CNOT(0,1): swap ctrl=1 pair at store
                psi[s00] = a00; psi[s01] = a01; psi[s10] = a11; psi[s11] = a10;
            }
            __syncthreads();
        }

        // ---- passes k=1..6 (k=6 of last layer peeled below) ----
        const int kend = (l == NLAYERS - 1) ? 5 : 6;
#pragma unroll 1
        for (int k = 1; k <= kend; ++k) {
            const int SB = 12 - 2 * k;
            const int LO = 1 << SB;
            const int SL = swz(LO);
            const int SH = swz(LO << 1);
            const float4 A0 = gt4[2*(g0 + 2*k)],     B0 = gt4[2*(g0 + 2*k) + 1];
            const float4 A1 = gt4[2*(g0 + 2*k + 1)], B1 = gt4[2*(g0 + 2*k + 1) + 1];
            const float ax0=rfl(A0.x), ay0=rfl(A0.y), az0=rfl(A0.z), aw0=rfl(A0.w);
            const float bx0=rfl(B0.x), by0=rfl(B0.y), bz0=rfl(B0.z), bw0=rfl(B0.w);
            const float ax1=rfl(A1.x), ay1=rfl(A1.y), az1=rfl(A1.z), aw1=rfl(A1.w);
            const float bx1=rfl(B1.x), by1=rfl(B1.y), bz1=rfl(B1.z), bw1=rfl(B1.w);
#pragma unroll 1
            for (int q = t; q < NQUAD; q += TPB) {
                const int i00 = ((q >> SB) << (SB + 2)) | (q & (LO - 1));
                const int s00 = swz(i00);
                v2f a00 = psi[s00],      a01 = psi[s00 ^ SL];
                v2f a10 = psi[s00 ^ SH], a11 = psi[s00 ^ SH ^ SL];
                pgp(a00, a10, ax0,ay0,az0,aw0, bx0,by0,bz0,bw0);   // wire 2k
                pgp(a01, a11, ax0,ay0,az0,aw0, bx0,by0,bz0,bw0);
                pgp(a00, a01, ax1,ay1,az1,aw1, bx1,by1,bz1,bw1);   // wire 2k+1
                pgp(a10, a11, ax1,ay1,az1,aw1, bx1,by1,bz1,bw1);
                // CNOT(2k-1,2k) + CNOT(2k,2k+1) as one address XOR
                const bool cs = ((i00 >> (SB + 2)) & 1) != 0;
                const int e = s00 ^ (cs ? (SH ^ SL) : 0);
                psi[e] = a00; psi[e ^ SL] = a01;
                psi[e ^ (SH ^ SL)] = a10; psi[e ^ SH] = a11;
            }
            __syncthreads();
        }
    }

    // ---- peeled final pass: l=2, wires 12,13 (bits 1,0) + fused measure ----
    float acc = 0.f;
    {
        const int g0 = (NLAYERS - 1) * NW;
        const float4 A0 = gt4[2*(g0 + 12)], B0 = gt4[2*(g0 + 12) + 1];
        const float4 A1 = gt4[2*(g0 + 13)], B1 = gt4[2*(g0 + 13) + 1];
        const float ax0=rfl(A0.x), ay0=rfl(A0.y), az0=rfl(A0.z), aw0=rfl(A0.w);
        const float bx0=rfl(B0.x), by0=rfl(B0.y), bz0=rfl(B0.z), bw0=rfl(B0.w);
        const float ax1=rfl(A1.x), ay1=rfl(A1.y), az1=rfl(A1.z), aw1=rfl(A1.w);
        const float bx1=rfl(B1.x), by1=rfl(B1.y), bz1=rfl(B1.z), bw1=rfl(B1.w);

        // coefT: i00 bits 2..11 = t bits 0..9 -> wires 11..2
        float coefT = 0.f;
#pragma unroll
        for (int j = 0; j < 10; ++j)
            coefT += ((t >> j) & 1) ? -hws[11 - j] : hws[11 - j];
        const float h12 = hws[12], h13 = hws[13];
        const bool cs = (t & 1) != 0;       // bit2 of i00 = bit0 of q = t&1

#pragma unroll 1
        for (int c = 0; c < NQUAD / TPB; ++c) {
            const int q   = t + c * TPB;
            const int i00 = q << 2;
            const int s00 = swz(i00);       // SL=swz(1)=1, SH=swz(2)=2
            v2f a00 = psi[s00],     a01 = psi[s00 ^ 1];
            v2f a10 = psi[s00 ^ 2], a11 = psi[s00 ^ 3];
            pgp(a00, a10, ax0,ay0,az0,aw0, bx0,by0,bz0,bw0);   // wire 12 (bit 1)
            pgp(a01, a11, ax0,ay0,az0,aw0, bx0,by0,bz0,bw0);
            pgp(a00, a01, ax1,ay1,az1,aw1, bx1,by1,bz1,bw1);   // wire 13 (bit 0)
            pgp(a10, a11, ax1,ay1,az1,aw1, bx1,by1,bz1,bw1);
            // dest bits after CNOT(11,12)+CNOT(12,13):
            //  a00 -> cs?11:00, a01 -> cs?10:01, a10 -> cs?00:11, a11 -> cs?01:10
            float coefQ = coefT;
            coefQ += (c & 1) ? -hws[1] : hws[1];   // i00 bit 12 -> wire 1
            coefQ += (c & 2) ? -hws[0] : hws[0];   // i00 bit 13 -> wire 0
            const float cpp = coefQ + h12 + h13, cpm = coefQ + h12 - h13;
            const float cmp = coefQ - h12 + h13, cmm = coefQ - h12 - h13;
            const float c00 = cs ? cmm : cpp;
            const float c01 = cs ? cmp : cpm;
            const float c10 = cs ? cpp : cmm;
            const float c11v = cs ? cpm : cmp;
            acc += (a00.x*a00.x + a00.y*a00.y) * c00;
            acc += (a01.x*a01.x + a01.y*a01.y) * c01;
            acc += (a10.x*a10.x + a10.y*a10.y) * c10;
            acc += (a11.x*a11.x + a11.y*a11.y) * c11v;
        }
    }
#pragma unroll
    for (int off = 32; off > 0; off >>= 1)
        acc += __shfl_down(acc, off, 64);
    if (lane == 0) red[wave] = acc;
    __syncthreads();
    if (t == 0) {
        float s = 0.f;
#pragma unroll
        for (int i = 0; i < TPB / 64; ++i) s += red[i];
        out[b] = s + head_b[0];
    }
}

extern "C" void kernel_launch(void* const* d_in, const int* in_sizes, int n_in,
                              void* d_out, int out_size, void* d_ws, size_t ws_size,
                              hipStream_t stream) {
    const float* state_batch = (const float*)d_in[0];
    const float* var_params  = (const float*)d_in[1];
    const float* head_w      = (const float*)d_in[2];
    const float* head_b      = (const float*)d_in[3];
    float* out = (float*)d_out;
    qsim_kernel<<<dim3(out_size), dim3(TPB), 0, stream>>>(
        state_batch, var_params, head_w, head_b, out);
}

// Round 9
// 101.533 us; speedup vs baseline: 1.9242x; 1.0519x over previous
//
#include <hip/hip_runtime.h>

// Quantum circuit sim — RADIX-8 passes (3 wires/sweep), packed-fp32 math,
// CNOT chain folded into store-address XOR, final pass fused with measure.
//
// R8 post-mortem: VALU-bound with DS-pipe second (21 sweeps x 256 KiB/CU).
// Radix-8 cuts sweeps 21 -> 15 (5/layer: 4 octet passes + wires 12,13).
//
// B=256 blocks (1/CU), 1024 threads, state 2^14 complex64 in LDS (128 KiB).
// Wire w <-> bit (13-w). Octet pass p covers wires (3p,3p+1,3p+2) = bits
// (SB+2,SB+1,SB), SB = 11-3p. In-octet index o=(b2,b1,b0).
//   incoming CNOT(3p-1,3p): ctrl = i000 bit SB+3 = q bit SB (cs)
//   internal CNOT(3p,3p+1), CNOT(3p+1,3p+2)
// Composed destination perm d(o) = [0,1,3,2,7,6,4,5], cs=1 case = d^7
// -> store base e = s ^ (cs ? S2^S1^S0 : 0), fixed store order. Chain
// order c=0..12 == pass order (1q gates on later wires commute).
// Final pass (l=2, wires 12,13): gates + CNOT(11,12),(12,13) + measurement
// + linear head fused, accumulating |amp|^2 * coef(dest index) (R8 code).
//
// LDS swizzle slot = i ^ ((i>>4)&15) ^ ((i>>8)&15), GF2-linear. Lane->bank
// residue maps verified rank-5 (conflict-free b64) for all octet load AND
// store patterns incl. the cs-affine term; only the wires-12/13 quad loads
// are rank-4 (4-way) — small, as in R8.
// Small dynamic loop bodies; gates in SGPRs via readfirstlane (the R2-R6
// big-body regime spilled pathologically on this toolchain; FETCH_SIZE is
// the canary).

#define NW      14
#define NSTATE  (1 << NW)
#define NOCT    (NSTATE >> 3)   // 2048
#define NQUAD   (NSTATE >> 2)   // 4096
#define TPB     1024
#define NLAYERS 3
#define NGATES  (NLAYERS * NW)

typedef float v2f __attribute__((ext_vector_type(2)));

__device__ __forceinline__ int swz(int i) {
    return i ^ ((i >> 4) & 15) ^ ((i >> 8) & 15);
}
__device__ __forceinline__ v2f vswp(v2f a) { return __builtin_shufflevector(a, a, 1, 0); }
__device__ __forceinline__ v2f vspl(float x) { v2f r; r.x = x;  r.y = x; return r; }
__device__ __forceinline__ v2f vpm(float x)  { v2f r; r.x = -x; r.y = x; return r; }
__device__ __forceinline__ float rfl(float x) {
    return __int_as_float(__builtin_amdgcn_readfirstlane(__float_as_int(x)));
}

// complex 2x2 gate on (a,d); row0 = (x00+iy00, x01+iy01), row1 likewise
__device__ __forceinline__ void pgp(v2f& a, v2f& d,
                                    float x00, float y00, float x01, float y01,
                                    float x10, float y10, float x11, float y11) {
    const v2f sa = vswp(a), sd = vswp(d);
    const v2f na = vspl(x00) * a + vpm(y00) * sa + vspl(x01) * d + vpm(y01) * sd;
    const v2f nd = vspl(x10) * a + vpm(y10) * sa + vspl(x11) * d + vpm(y11) * sd;
    a = na; d = nd;
}

// (-i)^pop * p
__device__ __forceinline__ v2f mkamp(float p, int pop) {
    const int m = pop & 3;
    v2f r;
    r.x = (m == 0) ? p : ((m == 2) ? -p : 0.f);
    r.y = (m == 1) ? -p : ((m == 3) ? p : 0.f);
    return r;
}

// pull one gate (8 scalars) from LDS into SGPRs
#define GATE_SGPR(pre, g) \
    const float4 pre##A = gt4[2*(g)], pre##B = gt4[2*(g)+1]; \
    const float pre##0 = rfl(pre##A.x), pre##1 = rfl(pre##A.y), \
                pre##2 = rfl(pre##A.z), pre##3 = rfl(pre##A.w), \
                pre##4 = rfl(pre##B.x), pre##5 = rfl(pre##B.y), \
                pre##6 = rfl(pre##B.z), pre##7 = rfl(pre##B.w);

#define PGP(a, d, pre) pgp(a, d, pre##0,pre##1,pre##2,pre##3, pre##4,pre##5,pre##6,pre##7)

__global__ void __launch_bounds__(TPB)
qsim_kernel(const float* __restrict__ state_batch,   // [B, NW]
            const float* __restrict__ var_params,    // [NLAYERS, NW, 3]
            const float* __restrict__ head_w,        // [NW]
            const float* __restrict__ head_b,        // [1]
            float* __restrict__ out)                 // [B]
{
    __shared__ v2f    psi[NSTATE];          // 128 KiB
    __shared__ float4 gt4[NGATES * 2];      // fused RZ*RY matrices
    __shared__ float  rxc[NW], rxs[NW], hws[NW];
    __shared__ float  red[TPB / 64];

    const int t    = threadIdx.x;
    const int lane = t & 63;
    const int wave = t >> 6;
    const int b    = blockIdx.x;

    if (t < NW) {
        float s, c; sincosf(0.5f * state_batch[b * NW + t], &s, &c);
        rxc[t] = c; rxs[t] = s;
    }
    if (t >= 64 && t < 64 + NGATES) {
        const int g = t - 64;               // g = l*NW + w
        float sa, ca, sz, cz;
        sincosf(0.5f * var_params[g * 3 + 0], &sa, &ca);
        sincosf(0.5f * var_params[g * 3 + 1], &sz, &cz);
        gt4[2*g]   = make_float4( ca * cz, -ca * sz, -sa * cz,  sa * sz);
        gt4[2*g+1] = make_float4( sa * cz,  sa * sz,  ca * cz,  ca * sz);
    }
    if (t >= 128 && t < 128 + NW) hws[t - 128] = head_w[t - 128];
    __syncthreads();

#pragma unroll 1
    for (int l = 0; l < NLAYERS; ++l) {
        const int g0 = l * NW;

        // ---- octet passes p=0..3: wires (3p,3p+1,3p+2), SB = 11-3p ----
#pragma unroll 1
        for (int p = 0; p < 4; ++p) {
            const int SB = 11 - 3 * p;
            const int LO = 1 << SB;
            const int S0 = swz(LO), S1 = swz(LO << 1), S2 = swz(LO << 2);
            const int M  = S2 ^ S1 ^ S0;
            const int gw = g0 + 3 * p;
            GATE_SGPR(u, gw);       // wire 3p   (bit SB+2)
            GATE_SGPR(v, gw + 1);   // wire 3p+1 (bit SB+1)
            GATE_SGPR(w, gw + 2);   // wire 3p+2 (bit SB)

#pragma unroll 1
            for (int q = t; q < NOCT; q += TPB) {
                const int i000 = ((q >> SB) << (SB + 3)) | (q & (LO - 1));
                const int s = swz(i000);
                v2f a0, a1, a2, a3, a4, a5, a6, a7;
                if (l == 0 && p == 0) {
                    // RX product state; i000 = q, bits 0..10 -> wires 13..3
                    float base = 1.f; int pop = 0;
#pragma unroll
                    for (int j = 0; j < 11; ++j) {
                        const int bit = (q >> j) & 1;
                        base *= bit ? rxs[13 - j] : rxc[13 - j];
                        pop += bit;
                    }
                    const float c0 = rxc[0], s0 = rxs[0];
                    const float c1 = rxc[1], s1 = rxs[1];
                    const float c2 = rxc[2], s2 = rxs[2];
                    a0 = mkamp(base * c0 * c1 * c2, pop);
                    a1 = mkamp(base * c0 * c1 * s2, pop + 1);
                    a2 = mkamp(base * c0 * s1 * c2, pop + 1);
                    a3 = mkamp(base * c0 * s1 * s2, pop + 2);
                    a4 = mkamp(base * s0 * c1 * c2, pop + 1);
                    a5 = mkamp(base * s0 * c1 * s2, pop + 2);
                    a6 = mkamp(base * s0 * s1 * c2, pop + 2);
                    a7 = mkamp(base * s0 * s1 * s2, pop + 3);
                } else {
                    a0 = psi[s];           a1 = psi[s ^ S0];
                    a2 = psi[s ^ S1];      a3 = psi[s ^ S1 ^ S0];
                    a4 = psi[s ^ S2];      a5 = psi[s ^ S2 ^ S0];
                    a6 = psi[s ^ S2 ^ S1]; a7 = psi[s ^ M];
                }
                // gate wire 3p (b2)
                PGP(a0, a4, u); PGP(a1, a5, u); PGP(a2, a6, u); PGP(a3, a7, u);
                // gate wire 3p+1 (b1)
                PGP(a0, a2, v); PGP(a1, a3, v); PGP(a4, a6, v); PGP(a5, a7, v);
                // gate wire 3p+2 (b0)
                PGP(a0, a1, w); PGP(a2, a3, w); PGP(a4, a5, w); PGP(a6, a7, w);
                // CNOTs: incoming (p>0) + 2 internal == base XOR + fixed order
                const bool cs = (p > 0) && (((q >> SB) & 1) != 0);
                const int e = s ^ (cs ? M : 0);
                // d(o) = [0,1,3,2,7,6,4,5]
                psi[e]           = a0; psi[e ^ S0]      = a1;
                psi[e ^ S1 ^ S0] = a2; psi[e ^ S1]      = a3;
                psi[e ^ M]       = a4; psi[e ^ S2 ^ S1] = a5;
                psi[e ^ S2]      = a6; psi[e ^ S2 ^ S0] = a7;
            }
            __syncthreads();
        }

        // ---- wires 12,13 (bits 1,0): quad pass (layers 0,1 store back) ----
        if (l < NLAYERS - 1) {
            GATE_SGPR(u, g0 + 12);
            GATE_SGPR(v, g0 + 13);
#pragma unroll 1
            for (int q = t; q < NQUAD; q += TPB) {
                const int s = swz(q << 2);          // S0=1, S1=2
                v2f a0 = psi[s],     a1 = psi[s ^ 1];
                v2f a2 = psi[s ^ 2], a3 = psi[s ^ 3];
                PGP(a0, a2, u); PGP(a1, a3, u);     // wire 12 (b1)
                PGP(a0, a1, v); PGP(a2, a3, v);     // wire 13 (b0)
                // CNOT(11,12) [cs = i00 bit 2 = q bit 0] + CNOT(12,13)
                const bool cs = (q & 1) != 0;
                const int e = s ^ (cs ? 3 : 0);     // d(o) = [0,1,3,2]
                psi[e] = a0; psi[e ^ 1] = a1; psi[e ^ 3] = a2; psi[e ^ 2] = a3;
            }
            __syncthreads();
        }
    }

    // ---- peeled final pass: l=2, wires 12,13 + fused measurement (R8) ----
    float acc = 0.f;
    {
        const int g0 = (NLAYERS - 1) * NW;
        GATE_SGPR(u, g0 + 12);
        GATE_SGPR(v, g0 + 13);

        // coefT: i00 bits 2..11 = t bits 0..9 -> wires 11..2
        float coefT = 0.f;
#pragma unroll
        for (int j = 0; j < 10; ++j)
            coefT += ((t >> j) & 1) ? -hws[11 - j] : hws[11 - j];
        const float h12 = hws[12], h13 = hws[13];
        const bool cs = (t & 1) != 0;       // i00 bit 2 = q bit 0 = t&1

#pragma unroll 1
        for (int c = 0; c < NQUAD / TPB; ++c) {
            const int q   = t + c * TPB;
            const int s00 = swz(q << 2);
            v2f a00 = psi[s00],     a01 = psi[s00 ^ 1];
            v2f a10 = psi[s00 ^ 2], a11 = psi[s00 ^ 3];
            PGP(a00, a10, u); PGP(a01, a11, u);     // wire 12 (bit 1)
            PGP(a00, a01, v); PGP(a10, a11, v);     // wire 13 (bit 0)
            // dest bits after CNOT(11,12)+CNOT(12,13):
            //  a00 -> cs?11:00, a01 -> cs?10:01, a10 -> cs?00:11, a11 -> cs?01:10
            float coefQ = coefT;
            coefQ += (c & 1) ? -hws[1] : hws[1];    // i00 bit 12 -> wire 1
            coefQ += (c & 2) ? -hws[0] : hws[0];    // i00 bit 13 -> wire 0
            const float cpp = coefQ + h12 + h13, cpm = coefQ + h12 - h13;
            const float cmp = coefQ - h12 + h13, cmm = coefQ - h12 - h13;
            const float c00 = cs ? cmm : cpp;
            const float c01 = cs ? cmp : cpm;
            const float c10 = cs ? cpp : cmm;
            const float c11 = cs ? cpm : cmp;
            acc += (a00.x*a00.x + a00.y*a00.y) * c00;
            acc += (a01.x*a01.x + a01.y*a01.y) * c01;
            acc += (a10.x*a10.x + a10.y*a10.y) * c10;
            acc += (a11.x*a11.x + a11.y*a11.y) * c11;
        }
    }
#pragma unroll
    for (int off = 32; off > 0; off >>= 1)
        acc += __shfl_down(acc, off, 64);
    if (lane == 0) red[wave] = acc;
    __syncthreads();
    if (t == 0) {
        float s = 0.f;
#pragma unroll
        for (int i = 0; i < TPB / 64; ++i) s += red[i];
        out[b] = s + head_b[0];
    }
}

extern "C" void kernel_launch(void* const* d_in, const int* in_sizes, int n_in,
                              void* d_out, int out_size, void* d_ws, size_t ws_size,
                              hipStream_t stream) {
    const float* state_batch = (const float*)d_in[0];
    const float* var_params  = (const float*)d_in[1];
    const float* head_w      = (const float*)d_in[2];
    const float* head_b      = (const float*)d_in[3];
    float* out = (float*)d_out;
    qsim_kernel<<<dim3(out_size), dim3(TPB), 0, stream>>>(
        state_batch, var_params, head_w, head_b, out);
}

// Round 10
// 95.085 us; speedup vs baseline: 2.0547x; 1.0678x over previous
//
#include <hip/hip_runtime.h>

// Quantum circuit sim — RADIX-16 passes (4 wires/sweep), packed-fp32 math,
// CNOT chain folded into store-address XOR, final pass fused with measure.
//
// R9 post-mortem: DS traffic + barrier count scale with sweep count and are
// the dominant reducible cost. Radix-16 cuts sweeps 15 -> 12 (3 hexa passes
// + 1 quad pass per layer), with EXACTLY one 16-amp group per thread per
// pass (1024 groups, 1024 threads — no inner loop).
//
// B=256 blocks (1/CU), 1024 threads, state 2^14 complex64 in LDS (128 KiB).
// Wire w <-> bit (13-w). Hexa pass p (p=0,1,2) covers wires 4p..4p+3 =
// bits (SB+3..SB), SB = 10-4p. In-group index o = (b3,b2,b1,b0).
//   incoming CNOT(4p-1,4p): ctrl = i bit SB+4 = t bit SB (cs; auto-0 at p=0)
//   internal CNOT(4p,4p+1),(4p+1,4p+2),(4p+2,4p+3)
// Composed dest perm D(o) = prefix-xor = {0,1,3,2,7,6,4,5,15,14,12,13,
// 8,9,11,10}; D(o^8) = D(o)^15 -> store base e = s ^ (cs ? S3^S2^S1^S0 : 0),
// fixed store order. Chain order c=0..12 == pass order (commutation arg as
// R8/R9, verified absmax=0 there). Quad pass (wires 12,13) + fused
// measurement pass carried over verbatim from R9 (verified).
//
// LDS swizzle slot = i ^ ((i>>4)&15) ^ ((i>>8)&15) ^ ((i>>9)&16), GF2-linear.
// Lane->bank-residue maps: rank 5 (conflict-free b64) for all hexa loads and
// p0/p1 stores; p2 stores + quad passes rank 4 (2-way-equiv, ~free m136).
// Gates in SGPRs via readfirstlane; small dynamic loop bodies (R2-R6 big-
// body regime spilled pathologically; FETCH_SIZE is the spill canary).

#define NW      14
#define NSTATE  (1 << NW)
#define NQUAD   (NSTATE >> 2)   // 4096
#define TPB     1024
#define NLAYERS 3
#define NGATES  (NLAYERS * NW)

typedef float v2f __attribute__((ext_vector_type(2)));

__device__ __forceinline__ int swz(int i) {
    return i ^ ((i >> 4) & 15) ^ ((i >> 8) & 15) ^ ((i >> 9) & 16);
}
__device__ __forceinline__ v2f vswp(v2f a) { return __builtin_shufflevector(a, a, 1, 0); }
__device__ __forceinline__ v2f vspl(float x) { v2f r; r.x = x;  r.y = x; return r; }
__device__ __forceinline__ v2f vpm(float x)  { v2f r; r.x = -x; r.y = x; return r; }
__device__ __forceinline__ float rfl(float x) {
    return __int_as_float(__builtin_amdgcn_readfirstlane(__float_as_int(x)));
}

// complex 2x2 gate on (a,d); row0 = (x00+iy00, x01+iy01), row1 likewise
__device__ __forceinline__ void pgp(v2f& a, v2f& d,
                                    float x00, float y00, float x01, float y01,
                                    float x10, float y10, float x11, float y11) {
    const v2f sa = vswp(a), sd = vswp(d);
    const v2f na = vspl(x00) * a + vpm(y00) * sa + vspl(x01) * d + vpm(y01) * sd;
    const v2f nd = vspl(x10) * a + vpm(y10) * sa + vspl(x11) * d + vpm(y11) * sd;
    a = na; d = nd;
}

// (-i)^pop * p
__device__ __forceinline__ v2f mkamp(float p, int pop) {
    const int m = pop & 3;
    v2f r;
    r.x = (m == 0) ? p : ((m == 2) ? -p : 0.f);
    r.y = (m == 1) ? -p : ((m == 3) ? p : 0.f);
    return r;
}

// pull one gate (8 scalars) from LDS into SGPRs
#define GATE_SGPR(pre, g) \
    const float4 pre##A = gt4[2*(g)], pre##B = gt4[2*(g)+1]; \
    const float pre##0 = rfl(pre##A.x), pre##1 = rfl(pre##A.y), \
                pre##2 = rfl(pre##A.z), pre##3 = rfl(pre##A.w), \
                pre##4 = rfl(pre##B.x), pre##5 = rfl(pre##B.y), \
                pre##6 = rfl(pre##B.z), pre##7 = rfl(pre##B.w);

#define PGP(a, d, pre) pgp(a, d, pre##0,pre##1,pre##2,pre##3, pre##4,pre##5,pre##6,pre##7)

__global__ void __launch_bounds__(TPB)
qsim_kernel(const float* __restrict__ state_batch,   // [B, NW]
            const float* __restrict__ var_params,    // [NLAYERS, NW, 3]
            const float* __restrict__ head_w,        // [NW]
            const float* __restrict__ head_b,        // [1]
            float* __restrict__ out)                 // [B]
{
    __shared__ v2f    psi[NSTATE];          // 128 KiB
    __shared__ float4 gt4[NGATES * 2];      // fused RZ*RY matrices
    __shared__ float  rxc[NW], rxs[NW], hws[NW];
    __shared__ float  red[TPB / 64];

    const int t    = threadIdx.x;
    const int lane = t & 63;
    const int wave = t >> 6;
    const int b    = blockIdx.x;

    if (t < NW) {
        float s, c; sincosf(0.5f * state_batch[b * NW + t], &s, &c);
        rxc[t] = c; rxs[t] = s;
    }
    if (t >= 64 && t < 64 + NGATES) {
        const int g = t - 64;               // g = l*NW + w
        float sa, ca, sz, cz;
        sincosf(0.5f * var_params[g * 3 + 0], &sa, &ca);
        sincosf(0.5f * var_params[g * 3 + 1], &sz, &cz);
        gt4[2*g]   = make_float4( ca * cz, -ca * sz, -sa * cz,  sa * sz);
        gt4[2*g+1] = make_float4( sa * cz,  sa * sz,  ca * cz,  ca * sz);
    }
    if (t >= 128 && t < 128 + NW) hws[t - 128] = head_w[t - 128];
    __syncthreads();

#pragma unroll 1
    for (int l = 0; l < NLAYERS; ++l) {
        const int g0 = l * NW;

        // ---- hexa passes p=0..2: wires 4p..4p+3, bits SB+3..SB ----
#pragma unroll 1
        for (int p = 0; p < 3; ++p) {
            const int SB = 10 - 4 * p;
            const int LO = 1 << SB;
            const int S0 = swz(LO), S1 = swz(LO << 1);
            const int S2 = swz(LO << 2), S3 = swz(LO << 3);
            const int M  = S3 ^ S2 ^ S1 ^ S0;
            const int gw = g0 + 4 * p;
            GATE_SGPR(ga, gw);       // wire 4p   (bit SB+3)
            GATE_SGPR(gb, gw + 1);   // wire 4p+1 (bit SB+2)
            GATE_SGPR(gc, gw + 2);   // wire 4p+2 (bit SB+1)
            GATE_SGPR(gd, gw + 3);   // wire 4p+3 (bit SB)

            const int i0 = ((t >> SB) << (SB + 4)) | (t & (LO - 1));
            const int s  = swz(i0);

            v2f a0, a1, a2, a3, a4, a5, a6, a7;
            v2f a8, a9, aA, aB, aC, aD, aE, aF;
            if (l == 0 && p == 0) {
                // RX product state; i0 = t, bits 0..9 -> wires 13..4,
                // group bits 13..10 -> wires 0..3
                float base = 1.f; int pop = 0;
#pragma unroll
                for (int j = 0; j < 10; ++j) {
                    const int bit = (t >> j) & 1;
                    base *= bit ? rxs[13 - j] : rxc[13 - j];
                    pop += bit;
                }
                const float h00 = rxc[0]*rxc[1], h01 = rxc[0]*rxs[1];
                const float h10 = rxs[0]*rxc[1], h11 = rxs[0]*rxs[1];
                const float q00 = rxc[2]*rxc[3], q01 = rxc[2]*rxs[3];
                const float q10 = rxs[2]*rxc[3], q11 = rxs[2]*rxs[3];
                a0 = mkamp(base*h00*q00, pop);     a1 = mkamp(base*h00*q01, pop+1);
                a2 = mkamp(base*h00*q10, pop+1);   a3 = mkamp(base*h00*q11, pop+2);
                a4 = mkamp(base*h01*q00, pop+1);   a5 = mkamp(base*h01*q01, pop+2);
                a6 = mkamp(base*h01*q10, pop+2);   a7 = mkamp(base*h01*q11, pop+3);
                a8 = mkamp(base*h10*q00, pop+1);   a9 = mkamp(base*h10*q01, pop+2);
                aA = mkamp(base*h10*q10, pop+2);   aB = mkamp(base*h10*q11, pop+3);
                aC = mkamp(base*h11*q00, pop+2);   aD = mkamp(base*h11*q01, pop+3);
                aE = mkamp(base*h11*q10, pop+3);   aF = mkamp(base*h11*q11, pop+4);
            } else {
                a0 = psi[s];                a1 = psi[s ^ S0];
                a2 = psi[s ^ S1];           a3 = psi[s ^ S1 ^ S0];
                a4 = psi[s ^ S2];           a5 = psi[s ^ S2 ^ S0];
                a6 = psi[s ^ S2 ^ S1];      a7 = psi[s ^ S2 ^ S1 ^ S0];
                a8 = psi[s ^ S3];           a9 = psi[s ^ S3 ^ S0];
                aA = psi[s ^ S3 ^ S1];      aB = psi[s ^ S3 ^ S1 ^ S0];
                aC = psi[s ^ S3 ^ S2];      aD = psi[s ^ S3 ^ S2 ^ S0];
                aE = psi[s ^ S3 ^ S2 ^ S1]; aF = psi[s ^ M];
            }
            // wire 4p (bit SB+3): pairs (o, o|8)
            PGP(a0, a8, ga); PGP(a1, a9, ga); PGP(a2, aA, ga); PGP(a3, aB, ga);
            PGP(a4, aC, ga); PGP(a5, aD, ga); PGP(a6, aE, ga); PGP(a7, aF, ga);
            // wire 4p+1 (bit SB+2): pairs (o, o|4)
            PGP(a0, a4, gb); PGP(a1, a5, gb); PGP(a2, a6, gb); PGP(a3, a7, gb);
            PGP(a8, aC, gb); PGP(a9, aD, gb); PGP(aA, aE, gb); PGP(aB, aF, gb);
            // wire 4p+2 (bit SB+1): pairs (o, o|2)
            PGP(a0, a2, gc); PGP(a1, a3, gc); PGP(a4, a6, gc); PGP(a5, a7, gc);
            PGP(a8, aA, gc); PGP(a9, aB, gc); PGP(aC, aE, gc); PGP(aD, aF, gc);
            // wire 4p+3 (bit SB): pairs (o, o|1)
            PGP(a0, a1, gd); PGP(a2, a3, gd); PGP(a4, a5, gd); PGP(a6, a7, gd);
            PGP(a8, a9, gd); PGP(aA, aB, gd); PGP(aC, aD, gd); PGP(aE, aF, gd);
            // CNOTs: incoming (p>0; cs auto-0 at p=0 since t<1024) + 3 internal
            const bool cs = ((t >> SB) & 1) != 0;
            const int e = s ^ (cs ? M : 0);
            // D(o) = {0,1,3,2,7,6,4,5,15,14,12,13,8,9,11,10}
            psi[e]                = a0; psi[e ^ S0]           = a1;
            psi[e ^ S1 ^ S0]      = a2; psi[e ^ S1]           = a3;
            psi[e ^ S2 ^ S1 ^ S0] = a4; psi[e ^ S2 ^ S1]      = a5;
            psi[e ^ S2]           = a6; psi[e ^ S2 ^ S0]      = a7;
            psi[e ^ M]            = a8; psi[e ^ S3 ^ S2 ^ S1] = a9;
            psi[e ^ S3 ^ S2]      = aA; psi[e ^ S3 ^ S2 ^ S0] = aB;
            psi[e ^ S3]           = aC; psi[e ^ S3 ^ S0]      = aD;
            psi[e ^ S3 ^ S1 ^ S0] = aE; psi[e ^ S3 ^ S1]      = aF;
            __syncthreads();
        }

        // ---- wires 12,13 (bits 1,0): quad pass (layers 0,1 store back) ----
        if (l < NLAYERS - 1) {
            GATE_SGPR(u, g0 + 12);
            GATE_SGPR(v, g0 + 13);
#pragma unroll 1
            for (int q = t; q < NQUAD; q += TPB) {
                const int s = swz(q << 2);          // swz(1)=1, swz(2)=2
                v2f a0 = psi[s],     a1 = psi[s ^ 1];
                v2f a2 = psi[s ^ 2], a3 = psi[s ^ 3];
                PGP(a0, a2, u); PGP(a1, a3, u);     // wire 12 (b1)
                PGP(a0, a1, v); PGP(a2, a3, v);     // wire 13 (b0)
                // CNOT(11,12) [cs = i bit 2 = q bit 0] + CNOT(12,13)
                const bool cs = (q & 1) != 0;
                const int e = s ^ (cs ? 3 : 0);     // d(o) = [0,1,3,2]
                psi[e] = a0; psi[e ^ 1] = a1; psi[e ^ 3] = a2; psi[e ^ 2] = a3;
            }
            __syncthreads();
        }
    }

    // ---- peeled final pass: l=2, wires 12,13 + fused measurement (R9) ----
    float acc = 0.f;
    {
        const int g0 = (NLAYERS - 1) * NW;
        GATE_SGPR(u, g0 + 12);
        GATE_SGPR(v, g0 + 13);

        // coefT: i bits 2..11 = t bits 0..9 -> wires 11..2
        float coefT = 0.f;
#pragma unroll
        for (int j = 0; j < 10; ++j)
            coefT += ((t >> j) & 1) ? -hws[11 - j] : hws[11 - j];
        const float h12 = hws[12], h13 = hws[13];
        const bool cs = (t & 1) != 0;       // i bit 2 = q bit 0 = t&1

#pragma unroll 1
        for (int c = 0; c < NQUAD / TPB; ++c) {
            const int q   = t + c * TPB;
            const int s00 = swz(q << 2);
            v2f a00 = psi[s00],     a01 = psi[s00 ^ 1];
            v2f a10 = psi[s00 ^ 2], a11 = psi[s00 ^ 3];
            PGP(a00, a10, u); PGP(a01, a11, u);     // wire 12 (bit 1)
            PGP(a00, a01, v); PGP(a10, a11, v);     // wire 13 (bit 0)
            // dest bits after CNOT(11,12)+CNOT(12,13):
            //  a00 -> cs?11:00, a01 -> cs?10:01, a10 -> cs?00:11, a11 -> cs?01:10
            float coefQ = coefT;
            coefQ += (c & 1) ? -hws[1] : hws[1];    // i bit 12 -> wire 1
            coefQ += (c & 2) ? -hws[0] : hws[0];    // i bit 13 -> wire 0
            const float cpp = coefQ + h12 + h13, cpm = coefQ + h12 - h13;
            const float cmp = coefQ - h12 + h13, cmm = coefQ - h12 - h13;
            const float c00 = cs ? cmm : cpp;
            const float c01 = cs ? cmp : cpm;
            const float c10 = cs ? cpp : cmm;
            const float c11 = cs ? cpm : cmp;
            acc += (a00.x*a00.x + a00.y*a00.y) * c00;
            acc += (a01.x*a01.x + a01.y*a01.y) * c01;
            acc += (a10.x*a10.x + a10.y*a10.y) * c10;
            acc += (a11.x*a11.x + a11.y*a11.y) * c11;
        }
    }
#pragma unroll
    for (int off = 32; off > 0; off >>= 1)
        acc += __shfl_down(acc, off, 64);
    if (lane == 0) red[wave] = acc;
    __syncthreads();
    if (t == 0) {
        float s = 0.f;
#pragma unroll
        for (int i = 0; i < TPB / 64; ++i) s += red[i];
        out[b] = s + head_b[0];
    }
}

extern "C" void kernel_launch(void* const* d_in, const int* in_sizes, int n_in,
                              void* d_out, int out_size, void* d_ws, size_t ws_size,
                              hipStream_t stream) {
    const float* state_batch = (const float*)d_in[0];
    const float* var_params  = (const float*)d_in[1];
    const float* head_w      = (const float*)d_in[2];
    const float* head_b      = (const float*)d_in[3];
    float* out = (float*)d_out;
    qsim_kernel<<<dim3(out_size), dim3(TPB), 0, stream>>>(
        state_batch, var_params, head_w, head_b, out);
}

// Round 11
// 91.632 us; speedup vs baseline: 2.1321x; 1.0377x over previous
//
#include <hip/hip_runtime.h>

// Quantum circuit sim — radix-16 passes, 3 sweeps/layer (quad pass merged
// into p=2 via DPP lane gates), packed-fp32, CNOT chain folded into store
// addresses, final layer RZ-free (real gates), measurement fused in regs.
//
// R10 post-mortem: 45 us kernel, VALU 58%, DS second. This round:
// (1) wires 12,13 handled inside pass p=2: i bits 1,0 = lane bits 1,0 ->
//     gates are quad_perm DPP butterflies (VALU only, no DS). CNOT(11,12),
//     (12,13) extend the prefix-xor cascade into bits 1,0: store delta
//     Delta = (t1?1:0) ^ ((parity(o)^cs)?3:0), derived from the sequential
//     chain b4^=b5, b3^=b4', b2^=b3', b1^=b2', b0^=b1' with incoming
//     b5^=b6(cs). Sweeps 12 -> 9 (8 r/w + 1 read-only), barriers 11 -> 8.
// (2) final layer: all RZs commute to a diagonal D past the chain perm P;
//     |P D x|^2 = |x o sigma|^2 -> drop them. Layer-2 gates staged as pure
//     real RY: reg gate 4 pk-ops (vs 10), lane gate 2 pk + 2 dpp (vs 8).
//
// B=256 blocks (1/CU), 1024 threads, state 2^14 complex64 in LDS (128 KiB).
// Wire w <-> bit (13-w). Hexa pass p covers wires 4p..4p+3 = bits SB+3..SB,
// SB = 10-4p; one 16-amp group per thread. In-group dest perm
// D(o) = {0,1,3,2,7,6,4,5,15,14,12,13,8,9,11,10}, D(o^8)=D(o)^15.
// LDS swizzle slot = i ^ ((i>>4)&15) ^ ((i>>8)&15) ^ ((i>>9)&16), GF2-linear.
// Gates in SGPRs via readfirstlane; small dynamic loop bodies (R2-R6 big-
// body regime spilled pathologically; FETCH_SIZE is the spill canary).

#define NW      14
#define NSTATE  (1 << NW)
#define TPB     1024
#define NLAYERS 3
#define NGATES  (NLAYERS * NW)

typedef float v2f __attribute__((ext_vector_type(2)));

__device__ __forceinline__ int swz(int i) {
    return i ^ ((i >> 4) & 15) ^ ((i >> 8) & 15) ^ ((i >> 9) & 16);
}
__device__ __forceinline__ v2f vswp(v2f a) { return __builtin_shufflevector(a, a, 1, 0); }
__device__ __forceinline__ v2f vspl(float x) { v2f r; r.x = x;  r.y = x; return r; }
__device__ __forceinline__ v2f vpm(float x)  { v2f r; r.x = -x; r.y = x; return r; }
__device__ __forceinline__ float rfl(float x) {
    return __int_as_float(__builtin_amdgcn_readfirstlane(__float_as_int(x)));
}
// quad_perm DPP lane butterfly on a v2f (xor1: ctrl 0xB1, xor2: ctrl 0x4E)
template <int CTRL>
__device__ __forceinline__ v2f dpp2(v2f a) {
    v2f r;
    r.x = __int_as_float(__builtin_amdgcn_update_dpp(
              0, __float_as_int(a.x), CTRL, 0xF, 0xF, true));
    r.y = __int_as_float(__builtin_amdgcn_update_dpp(
              0, __float_as_int(a.y), CTRL, 0xF, 0xF, true));
    return r;
}

// complex 2x2 gate on (a,d)
__device__ __forceinline__ void pgp(v2f& a, v2f& d,
                                    float x00, float y00, float x01, float y01,
                                    float x10, float y10, float x11, float y11) {
    const v2f sa = vswp(a), sd = vswp(d);
    const v2f na = vspl(x00) * a + vpm(y00) * sa + vspl(x01) * d + vpm(y01) * sd;
    const v2f nd = vspl(x10) * a + vpm(y10) * sa + vspl(x11) * d + vpm(y11) * sd;
    a = na; d = nd;
}
// real 2x2 gate on (a,d)
__device__ __forceinline__ void pgr(v2f& a, v2f& d,
                                    float x00, float x01, float x10, float x11) {
    const v2f na = vspl(x00) * a + vspl(x01) * d;
    const v2f nd = vspl(x10) * a + vspl(x11) * d;
    a = na; d = nd;
}

__device__ __forceinline__ v2f mkamp(float p, int pop) {
    const int m = pop & 3;
    v2f r;
    r.x = (m == 0) ? p : ((m == 2) ? -p : 0.f);
    r.y = (m == 1) ? -p : ((m == 3) ? p : 0.f);
    return r;
}

#define GATE_SGPR(pre, g) \
    const float4 pre##A = gt4[2*(g)], pre##B = gt4[2*(g)+1]; \
    const float pre##0 = rfl(pre##A.x), pre##1 = rfl(pre##A.y), \
                pre##2 = rfl(pre##A.z), pre##3 = rfl(pre##A.w), \
                pre##4 = rfl(pre##B.x), pre##5 = rfl(pre##B.y), \
                pre##6 = rfl(pre##B.z), pre##7 = rfl(pre##B.w);

#define PGP(a, d, pre) pgp(a, d, pre##0,pre##1,pre##2,pre##3, pre##4,pre##5,pre##6,pre##7)
#define PGR(a, d, pre) pgr(a, d, pre##0,pre##2,pre##4,pre##6)

// complex lane gate (one amp): partner via DPP, coefs lane-selected VGPRs
#define LGC1(aX, CT) { const v2f p_ = dpp2<CT>(aX); \
    aX = vspl(cox)*aX + vpm(coy)*vswp(aX) + vspl(cpx)*p_ + vpm(cpy)*vswp(p_); }
#define LGC_ALL(CT) \
    LGC1(a0,CT) LGC1(a1,CT) LGC1(a2,CT) LGC1(a3,CT) \
    LGC1(a4,CT) LGC1(a5,CT) LGC1(a6,CT) LGC1(a7,CT) \
    LGC1(a8,CT) LGC1(a9,CT) LGC1(aA,CT) LGC1(aB,CT) \
    LGC1(aC,CT) LGC1(aD,CT) LGC1(aE,CT) LGC1(aF,CT)
// real lane gate: own coef = ca (row-sym), partner coef lane-selected
#define LGR1(aX, CT) { const v2f p_ = dpp2<CT>(aX); \
    aX = vspl(cor)*aX + vspl(cpr)*p_; }
#define LGR_ALL(CT) \
    LGR1(a0,CT) LGR1(a1,CT) LGR1(a2,CT) LGR1(a3,CT) \
    LGR1(a4,CT) LGR1(a5,CT) LGR1(a6,CT) LGR1(a7,CT) \
    LGR1(a8,CT) LGR1(a9,CT) LGR1(aA,CT) LGR1(aB,CT) \
    LGR1(aC,CT) LGR1(aD,CT) LGR1(aE,CT) LGR1(aF,CT)

// measurement: Dn = dest nibble (cs=0), par = parity(o)
#define MEAS(aX, Dn, par) { \
    const float m_ = ((Dn)&8?-h8:h8)+((Dn)&4?-h9:h9)+((Dn)&2?-h10:h10)+((Dn)&1?-h11:h11); \
    const float cf_ = coefHigh + sc*m_ + ((par)? -Wp : Wp); \
    acc += (aX.x*aX.x + aX.y*aX.y)*cf_; }

__global__ void __launch_bounds__(TPB)
qsim_kernel(const float* __restrict__ state_batch,   // [B, NW]
            const float* __restrict__ var_params,    // [NLAYERS, NW, 3]
            const float* __restrict__ head_w,        // [NW]
            const float* __restrict__ head_b,        // [1]
            float* __restrict__ out)                 // [B]
{
    __shared__ v2f    psi[NSTATE];          // 128 KiB
    __shared__ float4 gt4[NGATES * 2];
    __shared__ float  rxc[NW], rxs[NW], hws[NW];
    __shared__ float  red[TPB / 64];

    const int t    = threadIdx.x;
    const int lane = t & 63;
    const int wave = t >> 6;
    const int b    = blockIdx.x;

    if (t < NW) {
        float s, c; sincosf(0.5f * state_batch[b * NW + t], &s, &c);
        rxc[t] = c; rxs[t] = s;
    }
    if (t >= 64 && t < 64 + NGATES) {
        const int g = t - 64;               // g = l*NW + w
        float sa, ca, sz, cz;
        sincosf(0.5f * var_params[g * 3 + 0], &sa, &ca);
        if (g >= 2 * NW) { sz = 0.f; cz = 1.f; }   // final layer: RZ dropped
        else sincosf(0.5f * var_params[g * 3 + 1], &sz, &cz);
        gt4[2*g]   = make_float4( ca * cz, -ca * sz, -sa * cz,  sa * sz);
        gt4[2*g+1] = make_float4( sa * cz,  sa * sz,  ca * cz,  ca * sz);
    }
    if (t >= 128 && t < 128 + NW) hws[t - 128] = head_w[t - 128];
    __syncthreads();

    float acc = 0.f;

#pragma unroll 1
    for (int l = 0; l < NLAYERS; ++l) {
        const int g0 = l * NW;
#pragma unroll 1
        for (int p = 0; p < 3; ++p) {
            const int SB = 10 - 4 * p;
            const int LO = 1 << SB;
            const int S0 = swz(LO), S1 = swz(LO << 1);
            const int S2 = swz(LO << 2), S3 = swz(LO << 3);
            const int M  = S3 ^ S2 ^ S1 ^ S0;
            const int gw = g0 + 4 * p;
            GATE_SGPR(ga, gw); GATE_SGPR(gb, gw + 1);
            GATE_SGPR(gc, gw + 2); GATE_SGPR(gd, gw + 3);

            const int i0 = ((t >> SB) << (SB + 4)) | (t & (LO - 1));
            const int s  = swz(i0);

            v2f a0, a1, a2, a3, a4, a5, a6, a7;
            v2f a8, a9, aA, aB, aC, aD, aE, aF;
            if (l == 0 && p == 0) {
                float base = 1.f; int pop = 0;
#pragma unroll
                for (int j = 0; j < 10; ++j) {
                    const int bit = (t >> j) & 1;
                    base *= bit ? rxs[13 - j] : rxc[13 - j];
                    pop += bit;
                }
                const float h00 = rxc[0]*rxc[1], h01 = rxc[0]*rxs[1];
                const float h10 = rxs[0]*rxc[1], h11 = rxs[0]*rxs[1];
                const float q00 = rxc[2]*rxc[3], q01 = rxc[2]*rxs[3];
                const float q10 = rxs[2]*rxc[3], q11 = rxs[2]*rxs[3];
                a0 = mkamp(base*h00*q00, pop);     a1 = mkamp(base*h00*q01, pop+1);
                a2 = mkamp(base*h00*q10, pop+1);   a3 = mkamp(base*h00*q11, pop+2);
                a4 = mkamp(base*h01*q00, pop+1);   a5 = mkamp(base*h01*q01, pop+2);
                a6 = mkamp(base*h01*q10, pop+2);   a7 = mkamp(base*h01*q11, pop+3);
                a8 = mkamp(base*h10*q00, pop+1);   a9 = mkamp(base*h10*q01, pop+2);
                aA = mkamp(base*h10*q10, pop+2);   aB = mkamp(base*h10*q11, pop+3);
                aC = mkamp(base*h11*q00, pop+2);   aD = mkamp(base*h11*q01, pop+3);
                aE = mkamp(base*h11*q10, pop+3);   aF = mkamp(base*h11*q11, pop+4);
            } else {
                a0 = psi[s];                a1 = psi[s ^ S0];
                a2 = psi[s ^ S1];           a3 = psi[s ^ S1 ^ S0];
                a4 = psi[s ^ S2];           a5 = psi[s ^ S2 ^ S0];
                a6 = psi[s ^ S2 ^ S1];      a7 = psi[s ^ S2 ^ S1 ^ S0];
                a8 = psi[s ^ S3];           a9 = psi[s ^ S3 ^ S0];
                aA = psi[s ^ S3 ^ S1];      aB = psi[s ^ S3 ^ S1 ^ S0];
                aC = psi[s ^ S3 ^ S2];      aD = psi[s ^ S3 ^ S2 ^ S0];
                aE = psi[s ^ S3 ^ S2 ^ S1]; aF = psi[s ^ M];
            }

            if (l < NLAYERS - 1) {
                PGP(a0, a8, ga); PGP(a1, a9, ga); PGP(a2, aA, ga); PGP(a3, aB, ga);
                PGP(a4, aC, ga); PGP(a5, aD, ga); PGP(a6, aE, ga); PGP(a7, aF, ga);
                PGP(a0, a4, gb); PGP(a1, a5, gb); PGP(a2, a6, gb); PGP(a3, a7, gb);
                PGP(a8, aC, gb); PGP(a9, aD, gb); PGP(aA, aE, gb); PGP(aB, aF, gb);
                PGP(a0, a2, gc); PGP(a1, a3, gc); PGP(a4, a6, gc); PGP(a5, a7, gc);
                PGP(a8, aA, gc); PGP(a9, aB, gc); PGP(aC, aE, gc); PGP(aD, aF, gc);
                PGP(a0, a1, gd); PGP(a2, a3, gd); PGP(a4, a5, gd); PGP(a6, a7, gd);
                PGP(a8, a9, gd); PGP(aA, aB, gd); PGP(aC, aD, gd); PGP(aE, aF, gd);
            } else {    // final layer: real RY-only gates
                PGR(a0, a8, ga); PGR(a1, a9, ga); PGR(a2, aA, ga); PGR(a3, aB, ga);
                PGR(a4, aC, ga); PGR(a5, aD, ga); PGR(a6, aE, ga); PGR(a7, aF, ga);
                PGR(a0, a4, gb); PGR(a1, a5, gb); PGR(a2, a6, gb); PGR(a3, a7, gb);
                PGR(a8, aC, gb); PGR(a9, aD, gb); PGR(aA, aE, gb); PGR(aB, aF, gb);
                PGR(a0, a2, gc); PGR(a1, a3, gc); PGR(a4, a6, gc); PGR(a5, a7, gc);
                PGR(a8, aA, gc); PGR(a9, aB, gc); PGR(aC, aE, gc); PGR(aD, aF, gc);
                PGR(a0, a1, gd); PGR(a2, a3, gd); PGR(a4, a5, gd); PGR(a6, a7, gd);
                PGR(a8, a9, gd); PGR(aA, aB, gd); PGR(aC, aD, gd); PGR(aE, aF, gd);
            }

            if (p < 2) {
                // standard store: incoming CNOT cs + internal prefix-xor D(o)
                const bool cs = ((t >> SB) & 1) != 0;
                const int e = s ^ (cs ? M : 0);
                psi[e]                = a0; psi[e ^ S0]           = a1;
                psi[e ^ S1 ^ S0]      = a2; psi[e ^ S1]           = a3;
                psi[e ^ S2 ^ S1 ^ S0] = a4; psi[e ^ S2 ^ S1]      = a5;
                psi[e ^ S2]           = a6; psi[e ^ S2 ^ S0]      = a7;
                psi[e ^ M]            = a8; psi[e ^ S3 ^ S2 ^ S1] = a9;
                psi[e ^ S3 ^ S2]      = aA; psi[e ^ S3 ^ S2 ^ S0] = aB;
                psi[e ^ S3]           = aC; psi[e ^ S3 ^ S0]      = aD;
                psi[e ^ S3 ^ S1 ^ S0] = aE; psi[e ^ S3 ^ S1]      = aF;
                __syncthreads();
            } else if (l < NLAYERS - 1) {
                // lane gates wires 12 (bit1, xor2=0x4E) and 13 (bit0, xor1=0xB1)
                GATE_SGPR(gu, g0 + 12);
                GATE_SGPR(gv, g0 + 13);
                {
                    const bool hi = (t & 2) != 0;
                    const float cox = hi ? gu6 : gu0, coy = hi ? gu7 : gu1;
                    const float cpx = hi ? gu4 : gu2, cpy = hi ? gu5 : gu3;
                    LGC_ALL(0x4E)
                }
                {
                    const bool hi = (t & 1) != 0;
                    const float cox = hi ? gv6 : gv0, coy = hi ? gv7 : gv1;
                    const float cpx = hi ? gv4 : gv2, cpy = hi ? gv5 : gv3;
                    LGC_ALL(0xB1)
                }
                // extended store: chain through bits 1,0
                // Delta = (t1?1:0) ^ ((parity(o)^cs)?3:0)
                const bool cs = ((t >> SB) & 1) != 0;
                const int e = s ^ (cs ? (M ^ 3) : 0) ^ ((t >> 1) & 1);
                psi[e]                    = a0; psi[e ^ S0 ^ 3]           = a1;
                psi[e ^ S1 ^ S0 ^ 3]      = a2; psi[e ^ S1]               = a3;
                psi[e ^ S2 ^ S1 ^ S0 ^ 3] = a4; psi[e ^ S2 ^ S1]          = a5;
                psi[e ^ S2]               = a6; psi[e ^ S2 ^ S0 ^ 3]      = a7;
                psi[e ^ M ^ 3]            = a8; psi[e ^ S3 ^ S2 ^ S1]     = a9;
                psi[e ^ S3 ^ S2]          = aA; psi[e ^ S3 ^ S2 ^ S0 ^ 3] = aB;
                psi[e ^ S3]               = aC; psi[e ^ S3 ^ S0 ^ 3]      = aD;
                psi[e ^ S3 ^ S1 ^ S0 ^ 3] = aE; psi[e ^ S3 ^ S1]          = aF;
                __syncthreads();
            } else {
                // final layer p=2: real lane gates + fused measurement
                GATE_SGPR(gu, g0 + 12);
                GATE_SGPR(gv, g0 + 13);
                {
                    const float cor = gu0;                      // ca
                    const float cpr = (t & 2) ? gu4 : gu2;      // +sa / -sa
                    LGR_ALL(0x4E)
                }
                {
                    const float cor = gv0;
                    const float cpr = (t & 1) ? gv4 : gv2;
                    LGR_ALL(0xB1)
                }
                // measurement from registers, coef by DEST index
                const float h8 = hws[8], h9 = hws[9], h10 = hws[10], h11 = hws[11];
                const float h12 = hws[12], h13 = hws[13];
                float coefHigh = 0.f;           // wires 0..7 from t bits 9..2
#pragma unroll
                for (int j = 0; j < 8; ++j)
                    coefHigh += ((t >> (9 - j)) & 1) ? -hws[j] : hws[j];
                const bool cs = ((t >> SB) & 1) != 0;
                const float sc = cs ? -1.f : 1.f;
                const float w12_0 = (t & 2) ? -h12 : h12;           // bit1 = t1 (P=0)
                const float w13_0 = (((t >> 1) ^ t) & 1) ? -h13 : h13;  // bit0 = t0^t1
                const float Ssum = w12_0 + w13_0;
                const float Wp = cs ? -Ssum : Ssum;
                MEAS(a0, 0, 0)  MEAS(a1, 1, 1)  MEAS(a2, 3, 1)  MEAS(a3, 2, 0)
                MEAS(a4, 7, 1)  MEAS(a5, 6, 0)  MEAS(a6, 4, 0)  MEAS(a7, 5, 1)
                MEAS(a8, 15, 1) MEAS(a9, 14, 0) MEAS(aA, 12, 0) MEAS(aB, 13, 1)
                MEAS(aC, 8, 0)  MEAS(aD, 9, 1)  MEAS(aE, 11, 1) MEAS(aF, 10, 0)
            }
        }
    }

    // ---- block reduction + head ----
#pragma unroll
    for (int off = 32; off > 0; off >>= 1)
        acc += __shfl_down(acc, off, 64);
    if (lane == 0) red[wave] = acc;
    __syncthreads();
    if (t == 0) {
        float s = 0.f;
#pragma unroll
        for (int i = 0; i < TPB / 64; ++i) s += red[i];
        out[b] = s + head_b[0];
    }
}

extern "C" void kernel_launch(void* const* d_in, const int* in_sizes, int n_in,
                              void* d_out, int out_size, void* d_ws, size_t ws_size,
                              hipStream_t stream) {
    const float* state_batch = (const float*)d_in[0];
    const float* var_params  = (const float*)d_in[1];
    const float* head_w      = (const float*)d_in[2];
    const float* head_b      = (const float*)d_in[3];
    float* out = (float*)d_out;
    qsim_kernel<<<dim3(out_size), dim3(TPB), 0, stream>>>(
        state_batch, var_params, head_w, head_b, out);
}

// Round 12
// 81.730 us; speedup vs baseline: 2.3904x; 1.1211x over previous
//
#include <hip/hip_runtime.h>

// Quantum circuit sim — radix-16, 2 ENTANGLING layers only: layer 0 is
// single-qubit gates on |0..0> followed by the CNOT chain, i.e. a PRODUCT
// STATE composed with the prefix-xor permutation — evaluated directly in
// registers (no passes, no LDS, no barriers for layer 0).
//
//   post-layer-0 amp(i) = prod_w v_w[x_w],  v_w = RZ(z0_w) RY(y0_w) RX(x_w)|0>
//   x_w = d_w ^ d_{w-1}  (chain inverse; d_w = wire-w bit of i)
//
// Thread t owns the 16 amps of layer-1-pass-0's group (i = o<<10 | t):
//   x_{w>=5} thread-fixed -> 9-factor Base (cmul tree); x_w4 = t9^o0 ->
//   B0/B1; group part via shared subproducts (~42 cmults total).
//
// Everything else is R11 verbatim (verified absmax=0): 3 hexa passes/layer,
// packed-fp32 gates, CNOT chain folded into store-address XORs with
// D(o) = prefix-xor perm, wires 12,13 via DPP quad_perm inside p=2
// (extended store delta through bits 1,0), final layer RZ-free (real RY
// gates at 4 pk-ops), measurement + linear head fused in registers.
// Sweeps 9 -> 6, barriers 8 -> 5.
//
// LDS swizzle slot = i ^ ((i>>4)&15) ^ ((i>>8)&15) ^ ((i>>9)&16), GF2-linear.
// Gates in SGPRs via readfirstlane; no indexable per-thread arrays (R2-R6
// big-body regime spilled pathologically; FETCH_SIZE is the spill canary).

#define NW      14
#define NSTATE  (1 << NW)
#define TPB     1024
#define NLAYERS 3
#define NGATES  (NLAYERS * NW)

typedef float v2f __attribute__((ext_vector_type(2)));

__device__ __forceinline__ int swz(int i) {
    return i ^ ((i >> 4) & 15) ^ ((i >> 8) & 15) ^ ((i >> 9) & 16);
}
__device__ __forceinline__ v2f vswp(v2f a) { return __builtin_shufflevector(a, a, 1, 0); }
__device__ __forceinline__ v2f vspl(float x) { v2f r; r.x = x;  r.y = x; return r; }
__device__ __forceinline__ v2f vpm(float x)  { v2f r; r.x = -x; r.y = x; return r; }
__device__ __forceinline__ float rfl(float x) {
    return __int_as_float(__builtin_amdgcn_readfirstlane(__float_as_int(x)));
}
// complex multiply (a.x+i a.y)(b.x+i b.y)
__device__ __forceinline__ v2f cml(v2f a, v2f b) {
    return vspl(a.x) * b + vpm(a.y) * vswp(b);
}
// quad_perm DPP lane butterfly on a v2f (xor1: ctrl 0xB1, xor2: ctrl 0x4E)
template <int CTRL>
__device__ __forceinline__ v2f dpp2(v2f a) {
    v2f r;
    r.x = __int_as_float(__builtin_amdgcn_update_dpp(
              0, __float_as_int(a.x), CTRL, 0xF, 0xF, true));
    r.y = __int_as_float(__builtin_amdgcn_update_dpp(
              0, __float_as_int(a.y), CTRL, 0xF, 0xF, true));
    return r;
}

// complex 2x2 gate on (a,d)
__device__ __forceinline__ void pgp(v2f& a, v2f& d,
                                    float x00, float y00, float x01, float y01,
                                    float x10, float y10, float x11, float y11) {
    const v2f sa = vswp(a), sd = vswp(d);
    const v2f na = vspl(x00) * a + vpm(y00) * sa + vspl(x01) * d + vpm(y01) * sd;
    const v2f nd = vspl(x10) * a + vpm(y10) * sa + vspl(x11) * d + vpm(y11) * sd;
    a = na; d = nd;
}
// real 2x2 gate on (a,d)
__device__ __forceinline__ void pgr(v2f& a, v2f& d,
                                    float x00, float x01, float x10, float x11) {
    const v2f na = vspl(x00) * a + vspl(x01) * d;
    const v2f nd = vspl(x10) * a + vspl(x11) * d;
    a = na; d = nd;
}

#define GATE_SGPR(pre, g) \
    const float4 pre##A = gt4[2*(g)], pre##B = gt4[2*(g)+1]; \
    const float pre##0 = rfl(pre##A.x), pre##1 = rfl(pre##A.y), \
                pre##2 = rfl(pre##A.z), pre##3 = rfl(pre##A.w), \
                pre##4 = rfl(pre##B.x), pre##5 = rfl(pre##B.y), \
                pre##6 = rfl(pre##B.z), pre##7 = rfl(pre##B.w);

#define PGP(a, d, pre) pgp(a, d, pre##0,pre##1,pre##2,pre##3, pre##4,pre##5,pre##6,pre##7)
#define PGR(a, d, pre) pgr(a, d, pre##0,pre##2,pre##4,pre##6)

#define LGC1(aX, CT) { const v2f p_ = dpp2<CT>(aX); \
    aX = vspl(cox)*aX + vpm(coy)*vswp(aX) + vspl(cpx)*p_ + vpm(cpy)*vswp(p_); }
#define LGC_ALL(CT) \
    LGC1(a0,CT) LGC1(a1,CT) LGC1(a2,CT) LGC1(a3,CT) \
    LGC1(a4,CT) LGC1(a5,CT) LGC1(a6,CT) LGC1(a7,CT) \
    LGC1(a8,CT) LGC1(a9,CT) LGC1(aA,CT) LGC1(aB,CT) \
    LGC1(aC,CT) LGC1(aD,CT) LGC1(aE,CT) LGC1(aF,CT)
#define LGR1(aX, CT) { const v2f p_ = dpp2<CT>(aX); \
    aX = vspl(cor)*aX + vspl(cpr)*p_; }
#define LGR_ALL(CT) \
    LGR1(a0,CT) LGR1(a1,CT) LGR1(a2,CT) LGR1(a3,CT) \
    LGR1(a4,CT) LGR1(a5,CT) LGR1(a6,CT) LGR1(a7,CT) \
    LGR1(a8,CT) LGR1(a9,CT) LGR1(aA,CT) LGR1(aB,CT) \
    LGR1(aC,CT) LGR1(aD,CT) LGR1(aE,CT) LGR1(aF,CT)

// measurement: Dn = dest nibble (cs=0), par = parity(o)
#define MEAS(aX, Dn, par) { \
    const float m_ = ((Dn)&8?-h8:h8)+((Dn)&4?-h9:h9)+((Dn)&2?-h10:h10)+((Dn)&1?-h11:h11); \
    const float cf_ = coefHigh + sc*m_ + ((par)? -Wp : Wp); \
    acc += (aX.x*aX.x + aX.y*aX.y)*cf_; }

__global__ void __launch_bounds__(TPB)
qsim_kernel(const float* __restrict__ state_batch,   // [B, NW]
            const float* __restrict__ var_params,    // [NLAYERS, NW, 3]
            const float* __restrict__ head_w,        // [NW]
            const float* __restrict__ head_b,        // [1]
            float* __restrict__ out)                 // [B]
{
    __shared__ v2f    psi[NSTATE];          // 128 KiB
    __shared__ float4 gt4[NGATES * 2];
    __shared__ v2f    vws[NW][2];           // per-wire RZ*RY*RX|0> columns
    __shared__ float  hws[NW];
    __shared__ float  red[TPB / 64];

    const int t    = threadIdx.x;
    const int lane = t & 63;
    const int wave = t >> 6;
    const int b    = blockIdx.x;

    // ---- stage per-wire init vectors (layer 0 + RX fused), gates, head ----
    if (t < NW) {
        float sx, cx, sy, cy, sz, cz;
        sincosf(0.5f * state_batch[b * NW + t], &sx, &cx);
        sincosf(0.5f * var_params[t * 3 + 0], &sy, &cy);            // layer 0 RY
        sincosf(0.5f * var_params[t * 3 + 1], &sz, &cz);            // layer 0 RZ
        // RY * RX|0> = (cy*cx + i sy*sx,  sy*cx - i cy*sx)
        const float tr = cy * cx, ti = sy * sx;
        const float br = sy * cx, bi = -cy * sx;
        v2f v0, v1;
        v0.x = cz * tr + sz * ti;  v0.y = cz * ti - sz * tr;        // *e^{-iz}
        v1.x = cz * br - sz * bi;  v1.y = cz * bi + sz * br;        // *e^{+iz}
        vws[t][0] = v0; vws[t][1] = v1;
    }
    if (t >= 64 && t < 64 + NGATES) {
        const int g = t - 64;               // g = l*NW + w; layer 0 unused
        if (g >= NW) {
            float sa, ca, sz, cz;
            sincosf(0.5f * var_params[g * 3 + 0], &sa, &ca);
            if (g >= 2 * NW) { sz = 0.f; cz = 1.f; }   // final layer: RZ dropped
            else sincosf(0.5f * var_params[g * 3 + 1], &sz, &cz);
            gt4[2*g]   = make_float4( ca * cz, -ca * sz, -sa * cz,  sa * sz);
            gt4[2*g+1] = make_float4( sa * cz,  sa * sz,  ca * cz,  ca * sz);
        }
    }
    if (t >= 128 && t < 128 + NW) hws[t - 128] = head_w[t - 128];
    __syncthreads();

    float acc = 0.f;

#pragma unroll 1
    for (int l = 1; l < NLAYERS; ++l) {
        const int g0 = l * NW;
#pragma unroll 1
        for (int p = 0; p < 3; ++p) {
            const int SB = 10 - 4 * p;
            const int LO = 1 << SB;
            const int S0 = swz(LO), S1 = swz(LO << 1);
            const int S2 = swz(LO << 2), S3 = swz(LO << 3);
            const int M  = S3 ^ S2 ^ S1 ^ S0;
            const int gw = g0 + 4 * p;
            GATE_SGPR(ga, gw); GATE_SGPR(gb, gw + 1);
            GATE_SGPR(gc, gw + 2); GATE_SGPR(gd, gw + 3);

            const int i0 = ((t >> SB) << (SB + 4)) | (t & (LO - 1));
            const int s  = swz(i0);

            v2f a0, a1, a2, a3, a4, a5, a6, a7;
            v2f a8, a9, aA, aB, aC, aD, aE, aF;
            if (l == 1 && p == 0) {
                // ---- post-layer-0 product state, chain perm folded ----
                // amp(i)=prod_w v_w[x_w], x_w = d_w^d_{w-1}; i = o<<10 | t
                // x_{w=5..13} = t_{13-w}^t_{14-w}; x_w4 = t9^o0;
                // x_w3 = o0^o1; x_w2 = o1^o2; x_w1 = o2^o3; x_w0 = o3
                v2f base = cml(vws[5][((t >> 8) ^ (t >> 9)) & 1],
                               vws[6][((t >> 7) ^ (t >> 8)) & 1]);
                v2f m2   = cml(vws[7][((t >> 6) ^ (t >> 7)) & 1],
                               vws[8][((t >> 5) ^ (t >> 6)) & 1]);
                v2f m3   = cml(vws[9][((t >> 4) ^ (t >> 5)) & 1],
                               vws[10][((t >> 3) ^ (t >> 4)) & 1]);
                v2f m4   = cml(vws[11][((t >> 2) ^ (t >> 3)) & 1],
                               vws[12][((t >> 1) ^ (t >> 2)) & 1]);
                base = cml(base, m2);
                m3   = cml(m3, m4);
                base = cml(base, m3);
                base = cml(base, vws[13][(t ^ (t >> 1)) & 1]);
                const int t9 = (t >> 9) & 1;
                const v2f B0 = cml(base, vws[4][t9]);
                const v2f B1 = cml(base, vws[4][t9 ^ 1]);
                const v2f w3B00 = cml(vws[3][0], B0);
                const v2f w3B01 = cml(vws[3][1], B1);
                const v2f w3B10 = cml(vws[3][1], B0);
                const v2f w3B11 = cml(vws[3][0], B1);
                v2f p_, t20, t21;
                p_ = cml(vws[0][0], vws[1][0]);
                t20 = cml(p_, vws[2][0]); t21 = cml(p_, vws[2][1]);
                a0 = cml(t20, w3B00); a1 = cml(t20, w3B01);
                a2 = cml(t21, w3B10); a3 = cml(t21, w3B11);
                p_ = cml(vws[0][0], vws[1][1]);
                t20 = cml(p_, vws[2][1]); t21 = cml(p_, vws[2][0]);
                a4 = cml(t20, w3B00); a5 = cml(t20, w3B01);
                a6 = cml(t21, w3B10); a7 = cml(t21, w3B11);
                p_ = cml(vws[0][1], vws[1][1]);
                t20 = cml(p_, vws[2][0]); t21 = cml(p_, vws[2][1]);
                a8 = cml(t20, w3B00); a9 = cml(t20, w3B01);
                aA = cml(t21, w3B10); aB = cml(t21, w3B11);
                p_ = cml(vws[0][1], vws[1][0]);
                t20 = cml(p_, vws[2][1]); t21 = cml(p_, vws[2][0]);
                aC = cml(t20, w3B00); aD = cml(t20, w3B01);
                aE = cml(t21, w3B10); aF = cml(t21, w3B11);
            } else {
                a0 = psi[s];                a1 = psi[s ^ S0];
                a2 = psi[s ^ S1];           a3 = psi[s ^ S1 ^ S0];
                a4 = psi[s ^ S2];           a5 = psi[s ^ S2 ^ S0];
                a6 = psi[s ^ S2 ^ S1];      a7 = psi[s ^ S2 ^ S1 ^ S0];
                a8 = psi[s ^ S3];           a9 = psi[s ^ S3 ^ S0];
                aA = psi[s ^ S3 ^ S1];      aB = psi[s ^ S3 ^ S1 ^ S0];
                aC = psi[s ^ S3 ^ S2];      aD = psi[s ^ S3 ^ S2 ^ S0];
                aE = psi[s ^ S3 ^ S2 ^ S1]; aF = psi[s ^ M];
            }

            if (l < NLAYERS - 1) {
                PGP(a0, a8, ga); PGP(a1, a9, ga); PGP(a2, aA, ga); PGP(a3, aB, ga);
                PGP(a4, aC, ga); PGP(a5, aD, ga); PGP(a6, aE, ga); PGP(a7, aF, ga);
                PGP(a0, a4, gb); PGP(a1, a5, gb); PGP(a2, a6, gb); PGP(a3, a7, gb);
                PGP(a8, aC, gb); PGP(a9, aD, gb); PGP(aA, aE, gb); PGP(aB, aF, gb);
                PGP(a0, a2, gc); PGP(a1, a3, gc); PGP(a4, a6, gc); PGP(a5, a7, gc);
                PGP(a8, aA, gc); PGP(a9, aB, gc); PGP(aC, aE, gc); PGP(aD, aF, gc);
                PGP(a0, a1, gd); PGP(a2, a3, gd); PGP(a4, a5, gd); PGP(a6, a7, gd);
                PGP(a8, a9, gd); PGP(aA, aB, gd); PGP(aC, aD, gd); PGP(aE, aF, gd);
            } else {    // final layer: real RY-only gates
                PGR(a0, a8, ga); PGR(a1, a9, ga); PGR(a2, aA, ga); PGR(a3, aB, ga);
                PGR(a4, aC, ga); PGR(a5, aD, ga); PGR(a6, aE, ga); PGR(a7, aF, ga);
                PGR(a0, a4, gb); PGR(a1, a5, gb); PGR(a2, a6, gb); PGR(a3, a7, gb);
                PGR(a8, aC, gb); PGR(a9, aD, gb); PGR(aA, aE, gb); PGR(aB, aF, gb);
                PGR(a0, a2, gc); PGR(a1, a3, gc); PGR(a4, a6, gc); PGR(a5, a7, gc);
                PGR(a8, aA, gc); PGR(a9, aB, gc); PGR(aC, aE, gc); PGR(aD, aF, gc);
                PGR(a0, a1, gd); PGR(a2, a3, gd); PGR(a4, a5, gd); PGR(a6, a7, gd);
                PGR(a8, a9, gd); PGR(aA, aB, gd); PGR(aC, aD, gd); PGR(aE, aF, gd);
            }

            if (p < 2) {
                const bool cs = ((t >> SB) & 1) != 0;
                const int e = s ^ (cs ? M : 0);
                psi[e]                = a0; psi[e ^ S0]           = a1;
                psi[e ^ S1 ^ S0]      = a2; psi[e ^ S1]           = a3;
                psi[e ^ S2 ^ S1 ^ S0] = a4; psi[e ^ S2 ^ S1]      = a5;
                psi[e ^ S2]           = a6; psi[e ^ S2 ^ S0]      = a7;
                psi[e ^ M]            = a8; psi[e ^ S3 ^ S2 ^ S1] = a9;
                psi[e ^ S3 ^ S2]      = aA; psi[e ^ S3 ^ S2 ^ S0] = aB;
                psi[e ^ S3]           = aC; psi[e ^ S3 ^ S0]      = aD;
                psi[e ^ S3 ^ S1 ^ S0] = aE; psi[e ^ S3 ^ S1]      = aF;
                __syncthreads();
            } else if (l < NLAYERS - 1) {
                // lane gates wires 12 (bit1, 0x4E) and 13 (bit0, 0xB1)
                GATE_SGPR(gu, g0 + 12);
                GATE_SGPR(gv, g0 + 13);
                {
                    const bool hi = (t & 2) != 0;
                    const float cox = hi ? gu6 : gu0, coy = hi ? gu7 : gu1;
                    const float cpx = hi ? gu4 : gu2, cpy = hi ? gu5 : gu3;
                    LGC_ALL(0x4E)
                }
                {
                    const bool hi = (t & 1) != 0;
                    const float cox = hi ? gv6 : gv0, coy = hi ? gv7 : gv1;
                    const float cpx = hi ? gv4 : gv2, cpy = hi ? gv5 : gv3;
                    LGC_ALL(0xB1)
                }
                // extended store: chain through bits 1,0
                const bool cs = ((t >> SB) & 1) != 0;
                const int e = s ^ (cs ? (M ^ 3) : 0) ^ ((t >> 1) & 1);
                psi[e]                    = a0; psi[e ^ S0 ^ 3]           = a1;
                psi[e ^ S1 ^ S0 ^ 3]      = a2; psi[e ^ S1]               = a3;
                psi[e ^ S2 ^ S1 ^ S0 ^ 3] = a4; psi[e ^ S2 ^ S1]          = a5;
                psi[e ^ S2]               = a6; psi[e ^ S2 ^ S0 ^ 3]      = a7;
                psi[e ^ M ^ 3]            = a8; psi[e ^ S3 ^ S2 ^ S1]     = a9;
                psi[e ^ S3 ^ S2]          = aA; psi[e ^ S3 ^ S2 ^ S0 ^ 3] = aB;
                psi[e ^ S3]               = aC; psi[e ^ S3 ^ S0 ^ 3]      = aD;
                psi[e ^ S3 ^ S1 ^ S0 ^ 3] = aE; psi[e ^ S3 ^ S1]          = aF;
                __syncthreads();
            } else {
                // final layer p=2: real lane gates + fused measurement
                GATE_SGPR(gu, g0 + 12);
                GATE_SGPR(gv, g0 + 13);
                {
                    const float cor = gu0;
                    const float cpr = (t & 2) ? gu4 : gu2;
                    LGR_ALL(0x4E)
                }
                {
                    const float cor = gv0;
                    const float cpr = (t & 1) ? gv4 : gv2;
                    LGR_ALL(0xB1)
                }
                const float h8 = hws[8], h9 = hws[9], h10 = hws[10], h11 = hws[11];
                const float h12 = hws[12], h13 = hws[13];
                float coefHigh = 0.f;           // wires 0..7 from t bits 9..2
#pragma unroll
                for (int j = 0; j < 8; ++j)
                    coefHigh += ((t >> (9 - j)) & 1) ? -hws[j] : hws[j];
                const bool cs = ((t >> SB) & 1) != 0;
                const float sc = cs ? -1.f : 1.f;
                const float w12_0 = (t & 2) ? -h12 : h12;
                const float w13_0 = (((t >> 1) ^ t) & 1) ? -h13 : h13;
                const float Ssum = w12_0 + w13_0;
                const float Wp = cs ? -Ssum : Ssum;
                MEAS(a0, 0, 0)  MEAS(a1, 1, 1)  MEAS(a2, 3, 1)  MEAS(a3, 2, 0)
                MEAS(a4, 7, 1)  MEAS(a5, 6, 0)  MEAS(a6, 4, 0)  MEAS(a7, 5, 1)
                MEAS(a8, 15, 1) MEAS(a9, 14, 0) MEAS(aA, 12, 0) MEAS(aB, 13, 1)
                MEAS(aC, 8, 0)  MEAS(aD, 9, 1)  MEAS(aE, 11, 1) MEAS(aF, 10, 0)
            }
        }
    }

    // ---- block reduction + head ----
#pragma unroll
    for (int off = 32; off > 0; off >>= 1)
        acc += __shfl_down(acc, off, 64);
    if (lane == 0) red[wave] = acc;
    __syncthreads();
    if (t == 0) {
        float s = 0.f;
#pragma unroll
        for (int i = 0; i < TPB / 64; ++i) s += red[i];
        out[b] = s + head_b[0];
    }
}

extern "C" void kernel_launch(void* const* d_in, const int* in_sizes, int n_in,
                              void* d_out, int out_size, void* d_ws, size_t ws_size,
                              hipStream_t stream) {
    const float* state_batch = (const float*)d_in[0];
    const float* var_params  = (const float*)d_in[1];
    const float* head_w      = (const float*)d_in[2];
    const float* head_b      = (const float*)d_in[3];
    float* out = (float*)d_out;
    qsim_kernel<<<dim3(out_size), dim3(TPB), 0, stream>>>(
        state_batch, var_params, head_w, head_b, out);
}

// Round 13
// 79.261 us; speedup vs baseline: 2.4649x; 1.0311x over previous
//
#include <hip/hip_runtime.h>

// Quantum circuit sim — radix-16, layer 0 folded into a product-state init
// (R12, verified absmax=0), and now layer-1 RZs factored OUT of the gate
// math: per-pass, the four RZ·RY gates == (4 real RY gates) x (one 4-wire
// diagonal with 16 slot-constant values e^{i*0.5*sum(+-z)}), since per-wire
// diagonals commute with RYs on other wires. The DPP wires (12,13) phase
// collapses to ONE per-thread constant e_t (amp bits 1,0 are thread-fixed).
// All gates (both layers) are now real RY matrices staged as a single
// float4 {ca,-sa,sa,ca} — half the gate-constant LDS reads + rfl's of R12.
//
// Structure (R11/R12, verified): 3 hexa passes/layer x 2 entangling layers,
// packed-fp32 v2f math, CNOT chain folded into store-address XORs with the
// prefix-xor perm D(o), wires 12,13 via quad_perm DPP inside p=2 (extended
// store delta through bits 1,0), final layer RZ-free by |.|^2 invariance,
// measurement + linear head fused in registers. 6 sweeps, 5 barriers.
//
// LDS swizzle slot = i ^ ((i>>4)&15) ^ ((i>>8)&15) ^ ((i>>9)&16), GF2-linear.
// Constants into SGPRs via readfirstlane; no indexable per-thread arrays
// (R2-R6 big-body regime spilled pathologically; FETCH_SIZE = spill canary).

#define NW      14
#define NSTATE  (1 << NW)
#define TPB     1024
#define NLAYERS 3

typedef float v2f __attribute__((ext_vector_type(2)));

__device__ __forceinline__ int swz(int i) {
    return i ^ ((i >> 4) & 15) ^ ((i >> 8) & 15) ^ ((i >> 9) & 16);
}
__device__ __forceinline__ v2f vswp(v2f a) { return __builtin_shufflevector(a, a, 1, 0); }
__device__ __forceinline__ v2f vspl(float x) { v2f r; r.x = x;  r.y = x; return r; }
__device__ __forceinline__ v2f vpm(float x)  { v2f r; r.x = -x; r.y = x; return r; }
__device__ __forceinline__ float rfl(float x) {
    return __int_as_float(__builtin_amdgcn_readfirstlane(__float_as_int(x)));
}
// complex multiply (a.x+i a.y)(b.x+i b.y)
__device__ __forceinline__ v2f cml(v2f a, v2f b) {
    return vspl(a.x) * b + vpm(a.y) * vswp(b);
}
template <int CTRL>
__device__ __forceinline__ v2f dpp2(v2f a) {
    v2f r;
    r.x = __int_as_float(__builtin_amdgcn_update_dpp(
              0, __float_as_int(a.x), CTRL, 0xF, 0xF, true));
    r.y = __int_as_float(__builtin_amdgcn_update_dpp(
              0, __float_as_int(a.y), CTRL, 0xF, 0xF, true));
    return r;
}
// real 2x2 gate on (a,d)
__device__ __forceinline__ void pgr(v2f& a, v2f& d,
                                    float x00, float x01, float x10, float x11) {
    const v2f na = vspl(x00) * a + vspl(x01) * d;
    const v2f nd = vspl(x10) * a + vspl(x11) * d;
    a = na; d = nd;
}

// real gate constants {ca,-sa,sa,ca} -> SGPRs
#define GATE_R(pre, g) \
    const float4 pre##V = gtr[g]; \
    const float pre##0 = rfl(pre##V.x), pre##1 = rfl(pre##V.y), \
                pre##2 = rfl(pre##V.z), pre##3 = rfl(pre##V.w);
#define PGR4(a, d, pre) pgr(a, d, pre##0, pre##1, pre##2, pre##3)

// 4-wire diagonal: one float4 = phases for slots (2k, 2k+1)
#define PH2(aE, aO, k) { \
    const float4 Z_ = zph4[zb + (k)]; \
    const float ex_ = rfl(Z_.x), ey_ = rfl(Z_.y); \
    const float ox_ = rfl(Z_.z), oy_ = rfl(Z_.w); \
    aE = vspl(ex_)*aE + vpm(ey_)*vswp(aE); \
    aO = vspl(ox_)*aO + vpm(oy_)*vswp(aO); }

// real DPP lane gate
#define LGR1(aX, CT) { const v2f p_ = dpp2<CT>(aX); \
    aX = vspl(cor)*aX + vspl(cpr)*p_; }
#define LGR_ALL(CT) \
    LGR1(a0,CT) LGR1(a1,CT) LGR1(a2,CT) LGR1(a3,CT) \
    LGR1(a4,CT) LGR1(a5,CT) LGR1(a6,CT) LGR1(a7,CT) \
    LGR1(a8,CT) LGR1(a9,CT) LGR1(aA,CT) LGR1(aB,CT) \
    LGR1(aC,CT) LGR1(aD,CT) LGR1(aE,CT) LGR1(aF,CT)

// per-thread wires-12/13 phase
#define ETA(aX) { aX = vspl(et.x)*aX + vpm(et.y)*vswp(aX); }
#define ETA_ALL \
    ETA(a0) ETA(a1) ETA(a2) ETA(a3) ETA(a4) ETA(a5) ETA(a6) ETA(a7) \
    ETA(a8) ETA(a9) ETA(aA) ETA(aB) ETA(aC) ETA(aD) ETA(aE) ETA(aF)

// measurement: Dn = dest nibble (cs=0), par = parity(o)
#define MEAS(aX, Dn, par) { \
    const float m_ = ((Dn)&8?-h8:h8)+((Dn)&4?-h9:h9)+((Dn)&2?-h10:h10)+((Dn)&1?-h11:h11); \
    const float cf_ = coefHigh + sc*m_ + ((par)? -Wp : Wp); \
    acc += (aX.x*aX.x + aX.y*aX.y)*cf_; }

__global__ void __launch_bounds__(TPB)
qsim_kernel(const float* __restrict__ state_batch,   // [B, NW]
            const float* __restrict__ var_params,    // [NLAYERS, NW, 3]
            const float* __restrict__ head_w,        // [NW]
            const float* __restrict__ head_b,        // [1]
            float* __restrict__ out)                 // [B]
{
    __shared__ v2f    psi[NSTATE];          // 128 KiB
    __shared__ float4 gtr[2 * NW];          // real RY gates, layers 1,2
    __shared__ float4 zph4[3 * 8];          // L1 per-pass 4-wire diag (16 slots)
    __shared__ v2f    zph12[4];             // L1 wires 12,13 diag by t&3
    __shared__ v2f    vws[NW][2];           // layer-0 product columns
    __shared__ float  hws[NW];
    __shared__ float  red[TPB / 64];

    const int t    = threadIdx.x;
    const int lane = t & 63;
    const int wave = t >> 6;
    const int b    = blockIdx.x;

    // ---- staging ----
    if (t < NW) {
        float sx, cx, sy, cy, sz, cz;
        sincosf(0.5f * state_batch[b * NW + t], &sx, &cx);
        sincosf(0.5f * var_params[t * 3 + 0], &sy, &cy);        // L0 RY
        sincosf(0.5f * var_params[t * 3 + 1], &sz, &cz);        // L0 RZ
        const float tr = cy * cx, ti = sy * sx;
        const float br = sy * cx, bi = -cy * sx;
        v2f v0, v1;
        v0.x = cz * tr + sz * ti;  v0.y = cz * ti - sz * tr;
        v1.x = cz * br - sz * bi;  v1.y = cz * bi + sz * br;
        vws[t][0] = v0; vws[t][1] = v1;
    }
    if (t >= 64 && t < 64 + 2 * NW) {       // real RY gates for layers 1,2
        const int g = t - 64;               // g = (l-1)*NW + w
        float sa, ca;
        sincosf(0.5f * var_params[(NW + g) * 3 + 0], &sa, &ca);
        gtr[g] = make_float4(ca, -sa, sa, ca);
    }
    if (t >= 128 && t < 128 + NW) hws[t - 128] = head_w[t - 128];
    if (t >= 192 && t < 240) {              // L1 per-pass 4-wire diagonals
        const int k = t - 192, p = k >> 4, o = k & 15;
        float ang = 0.f;
#pragma unroll
        for (int j = 0; j < 4; ++j) {       // o bit (3-j) <-> wire 4p+j
            const float z = var_params[(NW + 4 * p + j) * 3 + 1];
            ang += ((o >> (3 - j)) & 1) ? 0.5f * z : -0.5f * z;
        }
        float s_, c_; sincosf(ang, &s_, &c_);
        if (o & 1) { zph4[p * 8 + (o >> 1)].z = c_; zph4[p * 8 + (o >> 1)].w = s_; }
        else       { zph4[p * 8 + (o >> 1)].x = c_; zph4[p * 8 + (o >> 1)].y = s_; }
    }
    if (t >= 240 && t < 244) {              // L1 wires 12,13 diag by t&3
        const int k2 = t - 240;
        const float z12 = var_params[(NW + 12) * 3 + 1];
        const float z13 = var_params[(NW + 13) * 3 + 1];
        const float ang = ((k2 & 2) ? 0.5f * z12 : -0.5f * z12)
                        + ((k2 & 1) ? 0.5f * z13 : -0.5f * z13);
        float s_, c_; sincosf(ang, &s_, &c_);
        v2f e; e.x = c_; e.y = s_;
        zph12[k2] = e;
    }
    __syncthreads();

    float acc = 0.f;

#pragma unroll 1
    for (int l = 1; l < NLAYERS; ++l) {
        const int gl = (l - 1) * NW;
#pragma unroll 1
        for (int p = 0; p < 3; ++p) {
            const int SB = 10 - 4 * p;
            const int LO = 1 << SB;
            const int S0 = swz(LO), S1 = swz(LO << 1);
            const int S2 = swz(LO << 2), S3 = swz(LO << 3);
            const int M  = S3 ^ S2 ^ S1 ^ S0;
            const int zb = p * 8;
            GATE_R(ga, gl + 4 * p);     GATE_R(gb, gl + 4 * p + 1);
            GATE_R(gc, gl + 4 * p + 2); GATE_R(gd, gl + 4 * p + 3);

            const int i0 = ((t >> SB) << (SB + 4)) | (t & (LO - 1));
            const int s  = swz(i0);

            v2f a0, a1, a2, a3, a4, a5, a6, a7;
            v2f a8, a9, aA, aB, aC, aD, aE, aF;
            if (l == 1 && p == 0) {
                // ---- post-layer-0 product state, chain perm folded ----
                v2f base = cml(vws[5][((t >> 8) ^ (t >> 9)) & 1],
                               vws[6][((t >> 7) ^ (t >> 8)) & 1]);
                v2f m2   = cml(vws[7][((t >> 6) ^ (t >> 7)) & 1],
                               vws[8][((t >> 5) ^ (t >> 6)) & 1]);
                v2f m3   = cml(vws[9][((t >> 4) ^ (t >> 5)) & 1],
                               vws[10][((t >> 3) ^ (t >> 4)) & 1]);
                v2f m4   = cml(vws[11][((t >> 2) ^ (t >> 3)) & 1],
                               vws[12][((t >> 1) ^ (t >> 2)) & 1]);
                base = cml(base, m2);
                m3   = cml(m3, m4);
                base = cml(base, m3);
                base = cml(base, vws[13][(t ^ (t >> 1)) & 1]);
                const int t9 = (t >> 9) & 1;
                const v2f B0 = cml(base, vws[4][t9]);
                const v2f B1 = cml(base, vws[4][t9 ^ 1]);
                const v2f w3B00 = cml(vws[3][0], B0);
                const v2f w3B01 = cml(vws[3][1], B1);
                const v2f w3B10 = cml(vws[3][1], B0);
                const v2f w3B11 = cml(vws[3][0], B1);
                v2f p_, t20, t21;
                p_ = cml(vws[0][0], vws[1][0]);
                t20 = cml(p_, vws[2][0]); t21 = cml(p_, vws[2][1]);
                a0 = cml(t20, w3B00); a1 = cml(t20, w3B01);
                a2 = cml(t21, w3B10); a3 = cml(t21, w3B11);
                p_ = cml(vws[0][0], vws[1][1]);
                t20 = cml(p_, vws[2][1]); t21 = cml(p_, vws[2][0]);
                a4 = cml(t20, w3B00); a5 = cml(t20, w3B01);
                a6 = cml(t21, w3B10); a7 = cml(t21, w3B11);
                p_ = cml(vws[0][1], vws[1][1]);
                t20 = cml(p_, vws[2][0]); t21 = cml(p_, vws[2][1]);
                a8 = cml(t20, w3B00); a9 = cml(t20, w3B01);
                aA = cml(t21, w3B10); aB = cml(t21, w3B11);
                p_ = cml(vws[0][1], vws[1][0]);
                t20 = cml(p_, vws[2][1]); t21 = cml(p_, vws[2][0]);
                aC = cml(t20, w3B00); aD = cml(t20, w3B01);
                aE = cml(t21, w3B10); aF = cml(t21, w3B11);
            } else {
                a0 = psi[s];                a1 = psi[s ^ S0];
                a2 = psi[s ^ S1];           a3 = psi[s ^ S1 ^ S0];
                a4 = psi[s ^ S2];           a5 = psi[s ^ S2 ^ S0];
                a6 = psi[s ^ S2 ^ S1];      a7 = psi[s ^ S2 ^ S1 ^ S0];
                a8 = psi[s ^ S3];           a9 = psi[s ^ S3 ^ S0];
                aA = psi[s ^ S3 ^ S1];      aB = psi[s ^ S3 ^ S1 ^ S0];
                aC = psi[s ^ S3 ^ S2];      aD = psi[s ^ S3 ^ S2 ^ S0];
                aE = psi[s ^ S3 ^ S2 ^ S1]; aF = psi[s ^ M];
            }

            // 4 real RY gates (bits b3..b0)
            PGR4(a0, a8, ga); PGR4(a1, a9, ga); PGR4(a2, aA, ga); PGR4(a3, aB, ga);
            PGR4(a4, aC, ga); PGR4(a5, aD, ga); PGR4(a6, aE, ga); PGR4(a7, aF, ga);
            PGR4(a0, a4, gb); PGR4(a1, a5, gb); PGR4(a2, a6, gb); PGR4(a3, a7, gb);
            PGR4(a8, aC, gb); PGR4(a9, aD, gb); PGR4(aA, aE, gb); PGR4(aB, aF, gb);
            PGR4(a0, a2, gc); PGR4(a1, a3, gc); PGR4(a4, a6, gc); PGR4(a5, a7, gc);
            PGR4(a8, aA, gc); PGR4(a9, aB, gc); PGR4(aC, aE, gc); PGR4(aD, aF, gc);
            PGR4(a0, a1, gd); PGR4(a2, a3, gd); PGR4(a4, a5, gd); PGR4(a6, a7, gd);
            PGR4(a8, a9, gd); PGR4(aA, aB, gd); PGR4(aC, aD, gd); PGR4(aE, aF, gd);

            if (l == 1) {
                // 4-wire RZ diagonal (slot constants)
                PH2(a0, a1, 0) PH2(a2, a3, 1) PH2(a4, a5, 2) PH2(a6, a7, 3)
                PH2(a8, a9, 4) PH2(aA, aB, 5) PH2(aC, aD, 6) PH2(aE, aF, 7)
            }

            if (p < 2) {
                const bool cs = ((t >> SB) & 1) != 0;
                const int e = s ^ (cs ? M : 0);
                psi[e]                = a0; psi[e ^ S0]           = a1;
                psi[e ^ S1 ^ S0]      = a2; psi[e ^ S1]           = a3;
                psi[e ^ S2 ^ S1 ^ S0] = a4; psi[e ^ S2 ^ S1]      = a5;
                psi[e ^ S2]           = a6; psi[e ^ S2 ^ S0]      = a7;
                psi[e ^ M]            = a8; psi[e ^ S3 ^ S2 ^ S1] = a9;
                psi[e ^ S3 ^ S2]      = aA; psi[e ^ S3 ^ S2 ^ S0] = aB;
                psi[e ^ S3]           = aC; psi[e ^ S3 ^ S0]      = aD;
                psi[e ^ S3 ^ S1 ^ S0] = aE; psi[e ^ S3 ^ S1]      = aF;
                __syncthreads();
            } else if (l < NLAYERS - 1) {
                // real lane gates wires 12 (0x4E), 13 (0xB1) + e_t phase
                GATE_R(gu, gl + 12);
                GATE_R(gv, gl + 13);
                {
                    const float cor = gu0;
                    const float cpr = (t & 2) ? gu2 : gu1;
                    LGR_ALL(0x4E)
                }
                {
                    const float cor = gv0;
                    const float cpr = (t & 1) ? gv2 : gv1;
                    LGR_ALL(0xB1)
                }
                { const v2f et = zph12[t & 3]; ETA_ALL }
                // extended store: chain through bits 1,0
                const bool cs = ((t >> SB) & 1) != 0;
                const int e = s ^ (cs ? (M ^ 3) : 0) ^ ((t >> 1) & 1);
                psi[e]                    = a0; psi[e ^ S0 ^ 3]           = a1;
                psi[e ^ S1 ^ S0 ^ 3]      = a2; psi[e ^ S1]               = a3;
                psi[e ^ S2 ^ S1 ^ S0 ^ 3] = a4; psi[e ^ S2 ^ S1]          = a5;
                psi[e ^ S2]               = a6; psi[e ^ S2 ^ S0 ^ 3]      = a7;
                psi[e ^ M ^ 3]            = a8; psi[e ^ S3 ^ S2 ^ S1]     = a9;
                psi[e ^ S3 ^ S2]          = aA; psi[e ^ S3 ^ S2 ^ S0 ^ 3] = aB;
                psi[e ^ S3]               = aC; psi[e ^ S3 ^ S0 ^ 3]      = aD;
                psi[e ^ S3 ^ S1 ^ S0 ^ 3] = aE; psi[e ^ S3 ^ S1]          = aF;
                __syncthreads();
            } else {
                // final layer p=2: real lane gates + fused measurement
                GATE_R(gu, gl + 12);
                GATE_R(gv, gl + 13);
                {
                    const float cor = gu0;
                    const float cpr = (t & 2) ? gu2 : gu1;
                    LGR_ALL(0x4E)
                }
                {
                    const float cor = gv0;
                    const float cpr = (t & 1) ? gv2 : gv1;
                    LGR_ALL(0xB1)
                }
                const float h8 = hws[8], h9 = hws[9], h10 = hws[10], h11 = hws[11];
                const float h12 = hws[12], h13 = hws[13];
                float coefHigh = 0.f;           // wires 0..7 from t bits 9..2
#pragma unroll
                for (int j = 0; j < 8; ++j)
                    coefHigh += ((t >> (9 - j)) & 1) ? -hws[j] : hws[j];
                const bool cs = ((t >> SB) & 1) != 0;
                const float sc = cs ? -1.f : 1.f;
                const float w12_0 = (t & 2) ? -h12 : h12;
                const float w13_0 = (((t >> 1) ^ t) & 1) ? -h13 : h13;
                const float Ssum = w12_0 + w13_0;
                const float Wp = cs ? -Ssum : Ssum;
                MEAS(a0, 0, 0)  MEAS(a1, 1, 1)  MEAS(a2, 3, 1)  MEAS(a3, 2, 0)
                MEAS(a4, 7, 1)  MEAS(a5, 6, 0)  MEAS(a6, 4, 0)  MEAS(a7, 5, 1)
                MEAS(a8, 15, 1) MEAS(a9, 14, 0) MEAS(aA, 12, 0) MEAS(aB, 13, 1)
                MEAS(aC, 8, 0)  MEAS(aD, 9, 1)  MEAS(aE, 11, 1) MEAS(aF, 10, 0)
            }
        }
    }

    // ---- block reduction + head ----
#pragma unroll
    for (int off = 32; off > 0; off >>= 1)
        acc += __shfl_down(acc, off, 64);
    if (lane == 0) red[wave] = acc;
    __syncthreads();
    if (t == 0) {
        float s = 0.f;
#pragma unroll
        for (int i = 0; i < TPB / 64; ++i) s += red[i];
        out[b] = s + head_b[0];
    }
}

extern "C" void kernel_launch(void* const* d_in, const int* in_sizes, int n_in,
                              void* d_out, int out_size, void* d_ws, size_t ws_size,
                              hipStream_t stream) {
    const float* state_batch = (const float*)d_in[0];
    const float* var_params  = (const float*)d_in[1];
    const float* head_w      = (const float*)d_in[2];
    const float* head_b      = (const float*)d_in[3];
    float* out = (float*)d_out;
    qsim_kernel<<<dim3(out_size), dim3(TPB), 0, stream>>>(
        state_batch, var_params, head_w, head_b, out);
}